// Round 1
// baseline (2261.407 us; speedup 1.0000x reference)
//
#include <hip/hip_runtime.h>
#include <hip/hip_bf16.h>

// Problem constants
constexpr int BB = 32;    // batch
constexpr int TT = 512;   // decode steps
constexpr int NN = 512;   // nodes
constexpr int DD = 256;   // model dim
constexpr int HH = 8;     // heads
constexpr int DH = 32;    // head dim
#define NEG_INF (-1e9f)

// ---------------------------------------------------------------------------
// K0: graph_context[b][d] = (mean_n emb[b][n][:]) @ W_fixed
// grid=B, block=D
__global__ __launch_bounds__(256) void ctx_k(const float* __restrict__ emb,
                                             const float* __restrict__ Wf,
                                             float* __restrict__ ctx) {
    int b = blockIdx.x;
    int d = threadIdx.x;  // 0..255
    const float* eb = emb + (size_t)b * NN * DD + d;
    float s = 0.f;
    #pragma unroll 8
    for (int n = 0; n < NN; n++) s += eb[(size_t)n * DD];
    s *= (1.0f / NN);
    __shared__ float ms[DD];
    ms[d] = s;
    __syncthreads();
    float acc = 0.f;
    #pragma unroll 8
    for (int k = 0; k < DD; k++) acc += ms[k] * Wf[(size_t)k * DD + d];
    ctx[(size_t)b * DD + d] = acc;
}

// ---------------------------------------------------------------------------
// Generic tiled fp32 GEMM: C[M,NC] = A[M,K] @ Bm[K,NC]
// BM=64, BN=64, BK=16; 256 threads, 4x4 per thread.
// GATHER: A row r comes from emb[(r/TT)*NN + gidx[r]]
// BIAS:   adds bias[(r/TT)*NC + c]
// SPLIT3: NC=768 output split into three [*,256] buffers C0,C1,C2
template <int GATHER, int BIAS, int SPLIT3>
__global__ __launch_bounds__(256) void gemm_k(
    const float* __restrict__ A, const float* __restrict__ Bm,
    float* __restrict__ C0, float* __restrict__ C1, float* __restrict__ C2,
    const float* __restrict__ bias, const int* __restrict__ gidx,
    int M, int K, int NC) {
    __shared__ float As[64][17];  // padded: conflict-free column reads
    __shared__ float Bs[16][64];
    int tid = threadIdx.x;
    int tx = tid & 15, ty = tid >> 4;
    int m0 = blockIdx.x * 64;
    int n0 = blockIdx.y * 64;
    float c[4][4] = {};
    for (int k0 = 0; k0 < K; k0 += 16) {
        // A tile: 64 rows x 16 k, one float4 per thread
        {
            int rowi = tid >> 2, seg = tid & 3;
            int r = m0 + rowi;
            const float* ap;
            if (GATHER) {
                int b = r / TT;
                int node = gidx[r];
                ap = A + ((size_t)b * NN + node) * DD;
            } else {
                ap = A + (size_t)r * K;
            }
            float4 v = *(const float4*)(ap + k0 + seg * 4);
            As[rowi][seg * 4 + 0] = v.x;
            As[rowi][seg * 4 + 1] = v.y;
            As[rowi][seg * 4 + 2] = v.z;
            As[rowi][seg * 4 + 3] = v.w;
        }
        // B tile: 16 k x 64 cols
        {
            int rowk = tid >> 4, cs = (tid & 15) * 4;
            float4 v = *(const float4*)(Bm + (size_t)(k0 + rowk) * NC + n0 + cs);
            *(float4*)&Bs[rowk][cs] = v;
        }
        __syncthreads();
        #pragma unroll
        for (int kk = 0; kk < 16; kk++) {
            float a[4], bb[4];
            #pragma unroll
            for (int i = 0; i < 4; i++) a[i] = As[ty * 4 + i][kk];
            #pragma unroll
            for (int j = 0; j < 4; j++) bb[j] = Bs[kk][tx * 4 + j];
            #pragma unroll
            for (int i = 0; i < 4; i++)
                #pragma unroll
                for (int j = 0; j < 4; j++) c[i][j] += a[i] * bb[j];
        }
        __syncthreads();
    }
    #pragma unroll
    for (int i = 0; i < 4; i++) {
        int r = m0 + ty * 4 + i;
        #pragma unroll
        for (int j = 0; j < 4; j++) {
            int cidx = n0 + tx * 4 + j;
            float v = c[i][j];
            if (BIAS) v += bias[(size_t)(r / TT) * NC + cidx];
            if (SPLIT3) {
                int buf = cidx >> 8, cc = cidx & 255;
                float* p = buf == 0 ? C0 : (buf == 1 ? C1 : C2);
                p[(size_t)r * 256 + cc] = v;
            } else {
                C0[(size_t)r * NC + cidx] = v;
            }
        }
    }
}

// ---------------------------------------------------------------------------
// K3: multi-head glimpse attention. One block per (b, h, 8 t-rows).
// scores->mask->softmax->PV, scores live in LDS.
__global__ __launch_bounds__(256) void attn_k(
    const float* __restrict__ gq, const float* __restrict__ gk,
    const float* __restrict__ gv, const int* __restrict__ mask,
    float* __restrict__ heads) {
    const int TCH = 8;
    int nt = TT / TCH;  // 64
    int bid = blockIdx.x;
    int tchunk = bid % nt;
    int bh = bid / nt;
    int h = bh % HH;
    int b = bh / HH;
    int t0 = tchunk * TCH;

    __shared__ float qs[TCH][DH];
    __shared__ float ss[TCH][NN];  // 16 KB

    int tid = threadIdx.x;
    {
        int row = tid >> 5, dh = tid & 31;
        qs[row][dh] = gq[((size_t)(b * TT + t0 + row)) * DD + h * DH + dh];
    }
    __syncthreads();

    int row = tid >> 5;  // 0..7
    int g = tid & 31;
    const float scale = 0.17677669529663687f;  // 1/sqrt(32)
    const float* kb = gk + (size_t)b * NN * DD + h * DH;
    // scores
    for (int j = 0; j < 16; j++) {
        int n = j * 32 + g;
        const float4* kp = (const float4*)(kb + (size_t)n * DD);
        float acc = 0.f;
        #pragma unroll
        for (int dq = 0; dq < 8; dq++) {
            float4 kv = kp[dq];
            acc += qs[row][dq * 4 + 0] * kv.x + qs[row][dq * 4 + 1] * kv.y +
                   qs[row][dq * 4 + 2] * kv.z + qs[row][dq * 4 + 3] * kv.w;
        }
        int m = mask[((size_t)(b * TT + t0 + row)) * NN + n];
        ss[row][n] = m ? acc * scale : NEG_INF;
    }
    __syncthreads();

    // softmax: wave w handles rows 2w, 2w+1
    int wave = tid >> 6, lane = tid & 63;
    for (int rr = wave * 2; rr < wave * 2 + 2; rr++) {
        float mx = NEG_INF;
        #pragma unroll
        for (int j = 0; j < 8; j++) mx = fmaxf(mx, ss[rr][lane + j * 64]);
        #pragma unroll
        for (int o = 32; o > 0; o >>= 1) mx = fmaxf(mx, __shfl_xor(mx, o));
        float e[8];
        float sum = 0.f;
        #pragma unroll
        for (int j = 0; j < 8; j++) {
            e[j] = __expf(ss[rr][lane + j * 64] - mx);
            sum += e[j];
        }
        #pragma unroll
        for (int o = 32; o > 0; o >>= 1) sum += __shfl_xor(sum, o);
        float inv = 1.0f / sum;
        #pragma unroll
        for (int j = 0; j < 8; j++) ss[rr][lane + j * 64] = e[j] * inv;
    }
    __syncthreads();

    // PV
    {
        int dh = tid & 31;
        const float* vb = gv + (size_t)b * NN * DD + h * DH + dh;
        float acc = 0.f;
        #pragma unroll 8
        for (int n = 0; n < NN; n++) acc += ss[row][n] * vb[(size_t)n * DD];
        heads[((size_t)(b * TT + t0 + row)) * DD + h * DH + dh] = acc;
    }
}

// ---------------------------------------------------------------------------
// K5: pointer logits + tanh clip + mask + log_softmax. Block per (b, 8 rows).
__global__ __launch_bounds__(256) void logits_k(
    const float* __restrict__ glimpse, const float* __restrict__ lk,
    const int* __restrict__ mask, float* __restrict__ out) {
    const int TCH = 8;
    int nt = TT / TCH;
    int b = blockIdx.x / nt;
    int t0 = (blockIdx.x % nt) * TCH;
    __shared__ float gs[TCH][DD];  // 8 KB
    __shared__ float ls[TCH][NN];  // 16 KB
    int tid = threadIdx.x;
    #pragma unroll
    for (int i = 0; i < 8; i++) {
        int idx = tid + i * 256;
        int row = idx >> 8, d = idx & 255;
        gs[row][d] = glimpse[((size_t)(b * TT + t0 + row)) * DD + d];
    }
    __syncthreads();
    int row = tid >> 5, g = tid & 31;
    const float* lkb = lk + (size_t)b * NN * DD;
    for (int j = 0; j < 16; j++) {
        int n = j * 32 + g;
        const float4* kp = (const float4*)(lkb + (size_t)n * DD);
        float acc = 0.f;
        #pragma unroll
        for (int dq = 0; dq < 64; dq++) {
            float4 kv = kp[dq];
            acc += gs[row][dq * 4 + 0] * kv.x + gs[row][dq * 4 + 1] * kv.y +
                   gs[row][dq * 4 + 2] * kv.z + gs[row][dq * 4 + 3] * kv.w;
        }
        float lg = 10.0f * tanhf(acc * 0.0625f);  // 1/sqrt(256)=0.0625
        int m = mask[((size_t)(b * TT + t0 + row)) * NN + n];
        ls[row][n] = m ? lg : NEG_INF;
    }
    __syncthreads();
    int wave = tid >> 6, lane = tid & 63;
    for (int rr = wave * 2; rr < wave * 2 + 2; rr++) {
        float mx = NEG_INF;
        #pragma unroll
        for (int j = 0; j < 8; j++) mx = fmaxf(mx, ls[rr][lane + j * 64]);
        #pragma unroll
        for (int o = 32; o > 0; o >>= 1) mx = fmaxf(mx, __shfl_xor(mx, o));
        float sum = 0.f;
        #pragma unroll
        for (int j = 0; j < 8; j++) sum += __expf(ls[rr][lane + j * 64] - mx);
        #pragma unroll
        for (int o = 32; o > 0; o >>= 1) sum += __shfl_xor(sum, o);
        float lse = mx + __logf(sum);
        #pragma unroll
        for (int j = 0; j < 8; j++)
            out[((size_t)(b * TT + t0 + rr)) * NN + lane + j * 64] =
                ls[rr][lane + j * 64] - lse;
    }
}

// ---------------------------------------------------------------------------
extern "C" void kernel_launch(void* const* d_in, const int* in_sizes, int n_in,
                              void* d_out, int out_size, void* d_ws,
                              size_t ws_size, hipStream_t stream) {
    const float* emb = (const float*)d_in[0];   // [B,N,D]
    const int* cur   = (const int*)d_in[1];     // [B,T]
    const int* mask  = (const int*)d_in[2];     // [B,T,N]
    const float* Wn  = (const float*)d_in[3];   // [D,3D]
    const float* Wf  = (const float*)d_in[4];   // [D,D]
    const float* Ws  = (const float*)d_in[5];   // [D,D]
    const float* Wo  = (const float*)d_in[6];   // [D,D]
    float* out = (float*)d_out;

    const size_t SLAB = (size_t)BB * NN * DD;  // 4,194,304 floats
    float* ws = (float*)d_ws;
    float* gk      = ws;
    float* gv      = gk + SLAB;
    float* lk      = gv + SLAB;
    float* gq      = lk + SLAB;
    float* heads   = gq + SLAB;
    float* glimpse = heads + SLAB;
    float* ctx     = glimpse + SLAB;  // B*D floats

    // K0: graph context
    ctx_k<<<BB, 256, 0, stream>>>(emb, Wf, ctx);
    // K1: proj = emb @ W_node -> gk, gv, lk
    gemm_k<0, 0, 1><<<dim3((BB * NN) / 64, (3 * DD) / 64), 256, 0, stream>>>(
        emb, Wn, gk, gv, lk, nullptr, nullptr, BB * NN, DD, 3 * DD);
    // K2: glimpse_q = emb[cur] @ W_step + ctx
    gemm_k<1, 1, 0><<<dim3((BB * TT) / 64, DD / 64), 256, 0, stream>>>(
        emb, Ws, gq, nullptr, nullptr, ctx, cur, BB * TT, DD, DD);
    // K3: attention -> heads
    attn_k<<<BB * HH * (TT / 8), 256, 0, stream>>>(gq, gk, gv, mask, heads);
    // K4: glimpse = heads @ W_out
    gemm_k<0, 0, 0><<<dim3((BB * TT) / 64, DD / 64), 256, 0, stream>>>(
        heads, Wo, glimpse, nullptr, nullptr, nullptr, nullptr, BB * TT, DD, DD);
    // K5: pointer logits + log_softmax
    logits_k<<<BB * (TT / 8), 256, 0, stream>>>(glimpse, lk, mask, out);
}

// Round 2
// 356.084 us; speedup vs baseline: 6.3508x; 6.3508x over previous
//
#include <hip/hip_runtime.h>
#include <hip/hip_bf16.h>

constexpr int BB = 32;    // batch
constexpr int TT = 512;   // decode steps
constexpr int NN = 512;   // nodes
constexpr int DD = 256;   // model dim
constexpr int HH = 8;     // heads
constexpr int DH = 32;    // head dim
#define NEG_INF (-1e9f)

typedef __attribute__((ext_vector_type(8))) short bf16x8;
typedef __attribute__((ext_vector_type(4))) float f32x4;

__device__ inline ushort f2bf(float x) {
    union { float f; unsigned u; } c; c.f = x;
    unsigned u = c.u + 0x7fffu + ((c.u >> 16) & 1u);  // RNE
    return (ushort)(u >> 16);
}

// ---------------------------------------------------------------------------
// K0: graph_context[b][d] = (mean_n emb[b][n][:]) @ W_fixed   (fp32)
__global__ __launch_bounds__(256) void ctx_k(const float* __restrict__ emb,
                                             const float* __restrict__ Wf,
                                             float* __restrict__ ctx) {
    int b = blockIdx.x;
    int d = threadIdx.x;
    const float* eb = emb + (size_t)b * NN * DD + d;
    float s = 0.f;
    #pragma unroll 8
    for (int n = 0; n < NN; n++) s += eb[(size_t)n * DD];
    s *= (1.0f / NN);
    __shared__ float ms[DD];
    ms[d] = s;
    __syncthreads();
    float acc = 0.f;
    #pragma unroll 8
    for (int k = 0; k < DD; k++) acc += ms[k] * Wf[(size_t)k * DD + d];
    ctx[(size_t)b * DD + d] = acc;
}

// ---------------------------------------------------------------------------
// fp32 tiled GEMM, C[M,NC] = A[M,K] @ Bm[K,NC]. BM=BN=64, BK=16, 4x4/thread.
// GATHER: A row r = emb[(r/TT)*NN + gidx[r]]
// BIAS:   + bias[(r/TT)*NC + c]
// MODE 0: fp32 out O0.  MODE 1: bf16 out O0.
// MODE 2: NC=768 split: cols 0-255 -> gk bf16 [r][256]; 256-511 -> vT bf16
//         [(b*8+h)*32+dh][512]; 512-767 -> lk bf16 [r][256]
template <int GATHER, int BIAS, int MODE>
__global__ __launch_bounds__(256) void gemm_k(
    const float* __restrict__ A, const float* __restrict__ Bm,
    void* __restrict__ O0, void* __restrict__ O1, void* __restrict__ O2,
    const float* __restrict__ bias, const int* __restrict__ gidx,
    int M, int K, int NC) {
    __shared__ float As[64][17];
    __shared__ float Bs[16][64];
    int tid = threadIdx.x;
    int tx = tid & 15, ty = tid >> 4;
    int m0 = blockIdx.x * 64;
    int n0 = blockIdx.y * 64;
    float c[4][4] = {};
    for (int k0 = 0; k0 < K; k0 += 16) {
        {
            int rowi = tid >> 2, seg = tid & 3;
            int r = m0 + rowi;
            const float* ap;
            if (GATHER) {
                int b = r / TT;
                int node = gidx[r];
                ap = A + ((size_t)b * NN + node) * DD;
            } else {
                ap = A + (size_t)r * K;
            }
            float4 v = *(const float4*)(ap + k0 + seg * 4);
            As[rowi][seg * 4 + 0] = v.x;
            As[rowi][seg * 4 + 1] = v.y;
            As[rowi][seg * 4 + 2] = v.z;
            As[rowi][seg * 4 + 3] = v.w;
        }
        {
            int rowk = tid >> 4, cs = (tid & 15) * 4;
            float4 v = *(const float4*)(Bm + (size_t)(k0 + rowk) * NC + n0 + cs);
            *(float4*)&Bs[rowk][cs] = v;
        }
        __syncthreads();
        #pragma unroll
        for (int kk = 0; kk < 16; kk++) {
            float a[4], bb[4];
            #pragma unroll
            for (int i = 0; i < 4; i++) a[i] = As[ty * 4 + i][kk];
            #pragma unroll
            for (int j = 0; j < 4; j++) bb[j] = Bs[kk][tx * 4 + j];
            #pragma unroll
            for (int i = 0; i < 4; i++)
                #pragma unroll
                for (int j = 0; j < 4; j++) c[i][j] += a[i] * bb[j];
        }
        __syncthreads();
    }
    #pragma unroll
    for (int i = 0; i < 4; i++) {
        int r = m0 + ty * 4 + i;
        #pragma unroll
        for (int j = 0; j < 4; j++) {
            int cidx = n0 + tx * 4 + j;
            float v = c[i][j];
            if (BIAS) v += bias[(size_t)(r / TT) * NC + cidx];
            if (MODE == 0) {
                ((float*)O0)[(size_t)r * NC + cidx] = v;
            } else if (MODE == 1) {
                ((ushort*)O0)[(size_t)r * NC + cidx] = f2bf(v);
            } else {
                ushort uv = f2bf(v);
                int b = r >> 9, n = r & 511;  // NN == 512
                if (cidx < 256) {
                    ((ushort*)O0)[(size_t)r * 256 + cidx] = uv;
                } else if (cidx < 512) {
                    int col = cidx - 256;
                    ((ushort*)O1)[((size_t)(b * HH + (col >> 5)) * DH + (col & 31)) * NN + n] = uv;
                } else {
                    ((ushort*)O2)[(size_t)r * 256 + (cidx - 512)] = uv;
                }
            }
        }
    }
}

// ---------------------------------------------------------------------------
// K3: MFMA attention. grid = b*h*qchunk (32*8*8), 4 waves, 16 q rows/wave.
// Q,K from bf16 [row][256]; V from bf16 vT[(b*8+h)*32+dh][512]; heads fp32.
__global__ __launch_bounds__(256) void attn_mfma_k(
    const ushort* __restrict__ gq, const ushort* __restrict__ gk,
    const ushort* __restrict__ vT, const int* __restrict__ mask,
    float* __restrict__ heads) {
    int bid = blockIdx.x;
    int qc = bid & 7, h = (bid >> 3) & 7, b = bid >> 6;
    int tid = threadIdx.x;
    int w = tid >> 6, l = tid & 63;
    int lo = l & 15, hi = l >> 4;
    int t0 = qc * 64 + w * 16;

    __shared__ ushort Plds[4][16][512];  // 64 KB, wave-private slices

    // Q fragment: row = t0+lo, k = dh = hi*8..+8
    bf16x8 qf = *(const bf16x8*)(gq + ((size_t)(b * TT + t0 + lo)) * DD + h * DH + hi * 8);

    // QK^T: 32 n-chunks of 16
    f32x4 s[32];
    const f32x4 zero = {0.f, 0.f, 0.f, 0.f};
    const ushort* gkb = gk + (size_t)b * NN * DD + h * DH + hi * 8;
    #pragma unroll
    for (int c = 0; c < 32; c++) {
        bf16x8 kf = *(const bf16x8*)(gkb + (size_t)(c * 16 + lo) * DD);
        s[c] = __builtin_amdgcn_mfma_f32_16x16x32_bf16(qf, kf, zero, 0, 0, 0);
    }

    // mask + scale + row max
    const int* mrow = mask + ((size_t)(b * TT + t0)) * NN;
    const float sc = 0.17677669529663687f;  // 1/sqrt(32)
    float mx[4] = {NEG_INF, NEG_INF, NEG_INF, NEG_INF};
    #pragma unroll
    for (int c = 0; c < 32; c++) {
        #pragma unroll
        for (int r = 0; r < 4; r++) {
            int m = mrow[(size_t)(hi * 4 + r) * NN + c * 16 + lo];
            float v = m ? s[c][r] * sc : NEG_INF;
            s[c][r] = v;
            mx[r] = fmaxf(mx[r], v);
        }
    }
    #pragma unroll
    for (int r = 0; r < 4; r++) {
        #pragma unroll
        for (int o = 1; o < 16; o <<= 1) mx[r] = fmaxf(mx[r], __shfl_xor(mx[r], o));
    }
    float sum[4] = {0.f, 0.f, 0.f, 0.f};
    #pragma unroll
    for (int c = 0; c < 32; c++) {
        #pragma unroll
        for (int r = 0; r < 4; r++) {
            float e = __expf(s[c][r] - mx[r]);
            s[c][r] = e;
            sum[r] += e;
        }
    }
    #pragma unroll
    for (int r = 0; r < 4; r++) {
        #pragma unroll
        for (int o = 1; o < 16; o <<= 1) sum[r] += __shfl_xor(sum[r], o);
    }
    float inv[4];
    #pragma unroll
    for (int r = 0; r < 4; r++) inv[r] = 1.0f / sum[r];

    // P -> LDS (bf16, XOR-swizzled: elem-group g' = g ^ (row&7))
    #pragma unroll
    for (int c = 0; c < 32; c++) {
        int g = c * 2 + (lo >> 3);
        #pragma unroll
        for (int r = 0; r < 4; r++) {
            int row = hi * 4 + r;
            Plds[w][row][((g ^ (row & 7)) << 3) + (lo & 7)] = f2bf(s[c][r] * inv[r]);
        }
    }

    // PV: o[d][.] accumulates P[16 x 32chunk] @ V[32chunk x 16dh]
    f32x4 o[2] = {zero, zero};
    const ushort* vTb = vT + ((size_t)(b * HH + h) * DH + lo) * NN + hi * 8;
    #pragma unroll
    for (int c2 = 0; c2 < 16; c2++) {
        int g = c2 * 4 + hi;
        bf16x8 pf = *(const bf16x8*)&Plds[w][lo][(g ^ (lo & 7)) << 3];
        #pragma unroll
        for (int d = 0; d < 2; d++) {
            bf16x8 vf = *(const bf16x8*)(vTb + (size_t)d * 16 * NN + c2 * 32);
            o[d] = __builtin_amdgcn_mfma_f32_16x16x32_bf16(pf, vf, o[d], 0, 0, 0);
        }
    }
    #pragma unroll
    for (int d = 0; d < 2; d++)
        #pragma unroll
        for (int r = 0; r < 4; r++)
            heads[((size_t)(b * TT + t0 + hi * 4 + r)) * DD + h * DH + d * 16 + lo] = o[d][r];
}

// ---------------------------------------------------------------------------
// K5: MFMA pointer logits + tanh clip + mask + log_softmax.
// grid = b*tchunk (32*8), 4 waves, 16 t rows/wave. glimpse/lk bf16 [row][256].
__global__ __launch_bounds__(256) void logits_mfma_k(
    const ushort* __restrict__ glimpse, const ushort* __restrict__ lk,
    const int* __restrict__ mask, float* __restrict__ out) {
    int bid = blockIdx.x;
    int tc = bid & 7, b = bid >> 3;
    int tid = threadIdx.x;
    int w = tid >> 6, l = tid & 63;
    int lo = l & 15, hi = l >> 4;
    int t0 = tc * 64 + w * 16;

    // A fragments: 8 k-steps of 32 over D=256
    bf16x8 af[8];
    const ushort* gb = glimpse + ((size_t)(b * TT + t0 + lo)) * DD + hi * 8;
    #pragma unroll
    for (int ks = 0; ks < 8; ks++) af[ks] = *(const bf16x8*)(gb + ks * 32);

    const f32x4 zero = {0.f, 0.f, 0.f, 0.f};
    f32x4 s[32];
    const ushort* lkb = lk + (size_t)b * NN * DD + hi * 8;
    #pragma unroll
    for (int c = 0; c < 32; c++) {
        f32x4 acc = zero;
        const ushort* kr = lkb + (size_t)(c * 16 + lo) * DD;
        #pragma unroll
        for (int ks = 0; ks < 8; ks++) {
            bf16x8 bfr = *(const bf16x8*)(kr + ks * 32);
            acc = __builtin_amdgcn_mfma_f32_16x16x32_bf16(af[ks], bfr, acc, 0, 0, 0);
        }
        s[c] = acc;
    }

    // tanh clip + mask + row max
    const int* mrow = mask + ((size_t)(b * TT + t0)) * NN;
    float mx[4] = {NEG_INF, NEG_INF, NEG_INF, NEG_INF};
    #pragma unroll
    for (int c = 0; c < 32; c++) {
        #pragma unroll
        for (int r = 0; r < 4; r++) {
            int m = mrow[(size_t)(hi * 4 + r) * NN + c * 16 + lo];
            float v = 10.0f * tanhf(s[c][r] * 0.0625f);
            v = m ? v : NEG_INF;
            s[c][r] = v;
            mx[r] = fmaxf(mx[r], v);
        }
    }
    #pragma unroll
    for (int r = 0; r < 4; r++) {
        #pragma unroll
        for (int o = 1; o < 16; o <<= 1) mx[r] = fmaxf(mx[r], __shfl_xor(mx[r], o));
    }
    float sum[4] = {0.f, 0.f, 0.f, 0.f};
    #pragma unroll
    for (int c = 0; c < 32; c++) {
        #pragma unroll
        for (int r = 0; r < 4; r++) sum[r] += __expf(s[c][r] - mx[r]);
    }
    #pragma unroll
    for (int r = 0; r < 4; r++) {
        #pragma unroll
        for (int o = 1; o < 16; o <<= 1) sum[r] += __shfl_xor(sum[r], o);
    }
    float lse[4];
    #pragma unroll
    for (int r = 0; r < 4; r++) lse[r] = mx[r] + __logf(sum[r]);

    #pragma unroll
    for (int c = 0; c < 32; c++) {
        #pragma unroll
        for (int r = 0; r < 4; r++)
            out[((size_t)(b * TT + t0 + hi * 4 + r)) * NN + c * 16 + lo] = s[c][r] - lse[r];
    }
}

// ---------------------------------------------------------------------------
extern "C" void kernel_launch(void* const* d_in, const int* in_sizes, int n_in,
                              void* d_out, int out_size, void* d_ws,
                              size_t ws_size, hipStream_t stream) {
    const float* emb = (const float*)d_in[0];
    const int* cur   = (const int*)d_in[1];
    const int* mask  = (const int*)d_in[2];
    const float* Wn  = (const float*)d_in[3];
    const float* Wf  = (const float*)d_in[4];
    const float* Ws  = (const float*)d_in[5];
    const float* Wo  = (const float*)d_in[6];
    float* out = (float*)d_out;

    const size_t SLABE = (size_t)BB * NN * DD;  // 4,194,304 elements
    char* ws = (char*)d_ws;
    ushort* gk      = (ushort*)ws;                       // 8 MB bf16 [b*N+n][256]
    ushort* vT      = gk + SLABE;                        // 8 MB bf16 [(b*8+h)*32+dh][512]
    ushort* lkb     = vT + SLABE;                        // 8 MB bf16 [b*N+n][256]
    ushort* gq      = lkb + SLABE;                       // 8 MB bf16 [b*T+t][256]
    ushort* glimpse = gq + SLABE;                        // 8 MB bf16 [b*T+t][256]
    float* heads    = (float*)(glimpse + SLABE);         // 16 MB fp32
    float* ctx      = heads + SLABE;                     // 32 KB fp32

    // K0: graph context (fp32)
    ctx_k<<<BB, 256, 0, stream>>>(emb, Wf, ctx);
    // K1: proj = emb @ W_node -> gk(bf16), vT(bf16 transposed), lk(bf16)
    gemm_k<0, 0, 2><<<dim3((BB * NN) / 64, (3 * DD) / 64), 256, 0, stream>>>(
        emb, Wn, gk, vT, lkb, nullptr, nullptr, BB * NN, DD, 3 * DD);
    // K2: glimpse_q = emb[cur] @ W_step + ctx -> gq (bf16)
    gemm_k<1, 1, 1><<<dim3((BB * TT) / 64, DD / 64), 256, 0, stream>>>(
        emb, Ws, gq, nullptr, nullptr, ctx, cur, BB * TT, DD, DD);
    // K3: MFMA attention -> heads (fp32)
    attn_mfma_k<<<BB * HH * (TT / 64), 256, 0, stream>>>(gq, gk, vT, mask, heads);
    // K4: glimpse = heads @ W_out -> glimpse (bf16)
    gemm_k<0, 0, 1><<<dim3((BB * TT) / 64, DD / 64), 256, 0, stream>>>(
        heads, Wo, glimpse, nullptr, nullptr, nullptr, nullptr, BB * TT, DD, DD);
    // K5: MFMA pointer logits + log_softmax
    logits_mfma_k<<<BB * (TT / 64), 256, 0, stream>>>(glimpse, lkb, mask, out);
}

// Round 3
// 265.710 us; speedup vs baseline: 8.5108x; 1.3401x over previous
//
#include <hip/hip_runtime.h>
#include <hip/hip_bf16.h>

constexpr int BB = 32;    // batch
constexpr int TT = 512;   // decode steps
constexpr int NN = 512;   // nodes
constexpr int DD = 256;   // model dim
constexpr int HH = 8;     // heads
constexpr int DH = 32;    // head dim
#define NEG_INF (-1e9f)

typedef __attribute__((ext_vector_type(8))) short bf16x8;
typedef __attribute__((ext_vector_type(4))) float f32x4;

__device__ inline ushort f2bf(float x) {
    union { float f; unsigned u; } c; c.f = x;
    unsigned u = c.u + 0x7fffu + ((c.u >> 16) & 1u);  // RNE
    return (ushort)(u >> 16);
}
__device__ inline uint pk2(float a, float b) {
    return (uint)f2bf(a) | ((uint)f2bf(b) << 16);
}
__device__ inline float ulo(uint u) {
    union { uint u; float f; } c; c.u = u << 16; return c.f;
}
__device__ inline float uhi(uint u) {
    union { uint u; float f; } c; c.u = u & 0xffff0000u; return c.f;
}
__device__ inline float fast_tanh10(float x) {
    // 10*tanh(x), x clamped: tanh = 1 - 2/(e^{2x}+1)
    x = fminf(fmaxf(x, -20.f), 20.f);
    float e2 = __expf(2.f * x);
    return 10.f * (1.f - 2.f / (e2 + 1.f));
}

// ---------------------------------------------------------------------------
// P0: emb fp32 -> bf16 (vectorized)
__global__ __launch_bounds__(256) void cvt_emb_k(const float* __restrict__ in,
                                                 ushort* __restrict__ out) {
    int idx = blockIdx.x * 256 + threadIdx.x;  // total/4 threads
    float4 v = *(const float4*)(in + (size_t)idx * 4);
    ushort4 o = {f2bf(v.x), f2bf(v.y), f2bf(v.z), f2bf(v.w)};
    *(ushort4*)(out + (size_t)idx * 4) = o;
}

// P1: W[256][NC] f32 -> WT[NC][256] bf16  (LDS tile transpose)
__global__ __launch_bounds__(256) void twt_k(const float* __restrict__ W,
                                             ushort* __restrict__ WT, int NC) {
    __shared__ float t[32][33];
    int tx = threadIdx.x, ty = threadIdx.y;
    int x = blockIdx.x * 32 + tx;   // col n
    int y0 = blockIdx.y * 32;       // row k base
    #pragma unroll
    for (int j = 0; j < 4; j++)
        t[ty + j * 8][tx] = W[(size_t)(y0 + ty + j * 8) * NC + x];
    __syncthreads();
    #pragma unroll
    for (int j = 0; j < 4; j++)
        WT[(size_t)(blockIdx.x * 32 + ty + j * 8) * 256 + y0 + tx] =
            f2bf(t[tx][ty + j * 8]);
}

// P2: mask [B*T][512] int -> mbt [B*T][16] u32; word w bit c = mask[row][c*16+w]
__global__ __launch_bounds__(256) void packmask_k(const int* __restrict__ mask,
                                                  uint* __restrict__ mbt) {
    int idx = blockIdx.x * 256 + threadIdx.x;  // B*T*16
    int row = idx >> 4, w = idx & 15;
    const int* mr = mask + (size_t)row * NN + w;
    uint u = 0;
    #pragma unroll
    for (int c = 0; c < 32; c++) u |= (uint)(mr[c * 16] != 0) << c;
    mbt[idx] = u;
}

// ---------------------------------------------------------------------------
// K0: graph_context = mean(emb) @ W_fixed (fp32)
__global__ __launch_bounds__(1024) void ctx_k(const float* __restrict__ emb,
                                              const float* __restrict__ Wf,
                                              float* __restrict__ ctx) {
    int b = blockIdx.x;
    int tid = threadIdx.x;
    int part = tid >> 8, d = tid & 255;
    __shared__ float ps[4][256];
    const float* eb = emb + (size_t)b * NN * DD + d;
    float s = 0.f;
    #pragma unroll 8
    for (int i = 0; i < 128; i++) s += eb[(size_t)(part * 128 + i) * DD];
    ps[part][d] = s;
    __syncthreads();
    if (tid < 256) ps[0][d] = (ps[0][d] + ps[1][d] + ps[2][d] + ps[3][d]) * (1.f / NN);
    __syncthreads();
    if (tid < 256) {
        float acc = 0.f;
        #pragma unroll 8
        for (int k = 0; k < 256; k++) acc += ps[0][k] * Wf[(size_t)k * DD + d];
        ctx[(size_t)b * DD + d] = acc;
    }
}

// ---------------------------------------------------------------------------
// MFMA GEMM: C[M,NC] = A[M,256](bf16) @ W[256,NC] via WT[NC][256] bf16.
// 4 waves, wave = 16 rows; grid (M/64, NC/16/CPB).
// GATHER: A row = emb[b*512 + gidx[row]]. BIAS: + ctx[b][col] (f32).
// SPLIT: NC=768 -> gk [r][256] / vT [(b*8+h)*32+dh][512] / lk [r][256]
template <int GATHER, int BIAS, int SPLIT>
__global__ __launch_bounds__(256) void gemm_mfma_k(
    const ushort* __restrict__ A, const ushort* __restrict__ WT,
    ushort* __restrict__ O0, ushort* __restrict__ O1, ushort* __restrict__ O2,
    const float* __restrict__ bias, const int* __restrict__ gidx, int CPB) {
    int tid = threadIdx.x;
    int w = tid >> 6, l = tid & 63;
    int lo = l & 15, hi = l >> 4;
    int row0 = blockIdx.x * 64 + w * 16;
    int arow = row0 + lo;
    const ushort* ap;
    if (GATHER) {
        int b = arow >> 9;
        int node = gidx[arow];
        ap = A + ((size_t)(b * NN + node)) * DD;
    } else {
        ap = A + (size_t)arow * DD;
    }
    bf16x8 af[8];
    #pragma unroll
    for (int ks = 0; ks < 8; ks++)
        af[ks] = *(const bf16x8*)(ap + ks * 32 + hi * 8);

    const f32x4 zero = {0.f, 0.f, 0.f, 0.f};
    for (int c = 0; c < CPB; c++) {
        int cg = blockIdx.y * CPB + c;
        int col = cg * 16 + lo;
        const ushort* bp = WT + (size_t)col * 256 + hi * 8;
        f32x4 acc = zero;
        #pragma unroll
        for (int ks = 0; ks < 8; ks++)
            acc = __builtin_amdgcn_mfma_f32_16x16x32_bf16(
                af[ks], *(const bf16x8*)(bp + ks * 32), acc, 0, 0, 0);
        float v[4];
        #pragma unroll
        for (int r = 0; r < 4; r++) {
            v[r] = acc[r];
            if (BIAS) v[r] += bias[(size_t)(row0 >> 9) * DD + col];
        }
        if (SPLIT == 0) {
            #pragma unroll
            for (int r = 0; r < 4; r++)
                O0[(size_t)(row0 + 4 * hi + r) * DD + col] = f2bf(v[r]);
        } else {
            if (col < 256) {
                #pragma unroll
                for (int r = 0; r < 4; r++)
                    O0[(size_t)(row0 + 4 * hi + r) * 256 + col] = f2bf(v[r]);
            } else if (col < 512) {
                int cc = col - 256;
                int bh = (row0 >> 9) * HH + (cc >> 5);
                int dh = cc & 31;
                int n0 = (row0 + 4 * hi) & (NN - 1);
                ushort4 uv = {f2bf(v[0]), f2bf(v[1]), f2bf(v[2]), f2bf(v[3])};
                *(ushort4*)(O1 + ((size_t)bh * DH + dh) * NN + n0) = uv;
            } else {
                #pragma unroll
                for (int r = 0; r < 4; r++)
                    O2[(size_t)(row0 + 4 * hi + r) * 256 + (col - 512)] = f2bf(v[r]);
            }
        }
    }
}

// ---------------------------------------------------------------------------
// K3: MFMA attention. grid = B*H*8, 4 waves x 16 q-rows.
// Scores packed bf16 in regs; P via 4 wave-private 4KB LDS segments;
// O scaled by 1/sum at the end. heads out bf16.
__global__ __launch_bounds__(256) void attn2_k(
    const ushort* __restrict__ gq, const ushort* __restrict__ gk,
    const ushort* __restrict__ vT, const uint* __restrict__ mbt,
    ushort* __restrict__ headsB) {
    int bid = blockIdx.x;
    int qc = bid & 7, h = (bid >> 3) & 7, b = bid >> 6;
    int tid = threadIdx.x;
    int w = tid >> 6, l = tid & 63;
    int lo = l & 15, hi = l >> 4;
    int t0 = qc * 64 + w * 16;

    __shared__ ushort P[4][16][128];  // 16 KB, wave-private segments

    bf16x8 qf = *(const bf16x8*)(gq + ((size_t)(b * TT + t0 + lo)) * DD + h * DH + hi * 8);
    uint mw[4];
    #pragma unroll
    for (int r = 0; r < 4; r++)
        mw[r] = mbt[((size_t)(b * TT + t0 + 4 * hi + r)) * 16 + lo];

    const ushort* kb = gk + (size_t)b * NN * DD + h * DH + hi * 8;
    const f32x4 zero = {0.f, 0.f, 0.f, 0.f};
    const float sc = 0.17677669529663687f;  // 1/sqrt(32)
    float mx[4] = {NEG_INF, NEG_INF, NEG_INF, NEG_INF};
    uint su[64];
    #pragma unroll
    for (int c = 0; c < 32; c++) {
        bf16x8 kf = *(const bf16x8*)(kb + (size_t)(c * 16 + lo) * DD);
        f32x4 s = __builtin_amdgcn_mfma_f32_16x16x32_bf16(qf, kf, zero, 0, 0, 0);
        float v[4];
        #pragma unroll
        for (int r = 0; r < 4; r++) {
            v[r] = ((mw[r] >> c) & 1u) ? s[r] * sc : NEG_INF;
            mx[r] = fmaxf(mx[r], v[r]);
        }
        su[2 * c] = pk2(v[0], v[1]);
        su[2 * c + 1] = pk2(v[2], v[3]);
    }
    #pragma unroll
    for (int r = 0; r < 4; r++)
        #pragma unroll
        for (int o = 1; o < 16; o <<= 1) mx[r] = fmaxf(mx[r], __shfl_xor(mx[r], o));

    float sum[4] = {0.f, 0.f, 0.f, 0.f};
    f32x4 o0 = zero, o1 = zero;
    const ushort* vb = vT + ((size_t)(b * HH + h) * DH + lo) * NN + hi * 8;
    #pragma unroll
    for (int seg = 0; seg < 4; seg++) {
        #pragma unroll
        for (int cl = 0; cl < 8; cl++) {
            int c = seg * 8 + cl;
            float v[4] = {ulo(su[2 * c]), uhi(su[2 * c]), ulo(su[2 * c + 1]), uhi(su[2 * c + 1])};
            int g = 2 * cl + (lo >> 3);
            #pragma unroll
            for (int r = 0; r < 4; r++) {
                float e = __expf(v[r] - mx[r]);  // masked: exp(-1e9-mx) = 0
                sum[r] += e;
                int row = 4 * hi + r;
                P[w][row][((g ^ (row & 7)) << 3) + (lo & 7)] = f2bf(e);
            }
        }
        #pragma unroll
        for (int c2 = 0; c2 < 4; c2++) {
            int g2 = c2 * 4 + hi;
            bf16x8 pf = *(const bf16x8*)&P[w][lo][(g2 ^ (lo & 7)) << 3];
            bf16x8 vf0 = *(const bf16x8*)(vb + seg * 128 + c2 * 32);
            bf16x8 vf1 = *(const bf16x8*)(vb + (size_t)16 * NN + seg * 128 + c2 * 32);
            o0 = __builtin_amdgcn_mfma_f32_16x16x32_bf16(pf, vf0, o0, 0, 0, 0);
            o1 = __builtin_amdgcn_mfma_f32_16x16x32_bf16(pf, vf1, o1, 0, 0, 0);
        }
    }
    #pragma unroll
    for (int r = 0; r < 4; r++) {
        #pragma unroll
        for (int o = 1; o < 16; o <<= 1) sum[r] += __shfl_xor(sum[r], o);
    }
    #pragma unroll
    for (int r = 0; r < 4; r++) {
        float inv = 1.0f / sum[r];
        size_t orow = ((size_t)(b * TT + t0 + 4 * hi + r)) * DD + h * DH + lo;
        headsB[orow] = f2bf(o0[r] * inv);
        headsB[orow + 16] = f2bf(o1[r] * inv);
    }
}

// ---------------------------------------------------------------------------
// K5: MFMA pointer logits + tanh clip + mask + log_softmax. 1 wave/block,
// grid = B*32 (16 t-rows per block). Logits packed bf16 in regs.
__global__ __launch_bounds__(64) void logits2_k(
    const ushort* __restrict__ glimpse, const ushort* __restrict__ lk,
    const uint* __restrict__ mbt, float* __restrict__ out) {
    int bid = blockIdx.x;
    int b = bid >> 5;
    int t0 = (bid & 31) * 16;
    int l = threadIdx.x & 63;
    int lo = l & 15, hi = l >> 4;

    bf16x8 af[8];
    const ushort* gb = glimpse + ((size_t)(b * TT + t0 + lo)) * DD + hi * 8;
    #pragma unroll
    for (int ks = 0; ks < 8; ks++) af[ks] = *(const bf16x8*)(gb + ks * 32);
    uint mw[4];
    #pragma unroll
    for (int r = 0; r < 4; r++)
        mw[r] = mbt[((size_t)(b * TT + t0 + 4 * hi + r)) * 16 + lo];

    const f32x4 zero = {0.f, 0.f, 0.f, 0.f};
    const ushort* lkb = lk + (size_t)b * NN * DD + hi * 8;
    float mx[4] = {NEG_INF, NEG_INF, NEG_INF, NEG_INF};
    uint tu[64];
    #pragma unroll
    for (int c = 0; c < 32; c++) {
        f32x4 acc = zero;
        const ushort* kr = lkb + (size_t)(c * 16 + lo) * DD;
        #pragma unroll
        for (int ks = 0; ks < 8; ks++)
            acc = __builtin_amdgcn_mfma_f32_16x16x32_bf16(
                af[ks], *(const bf16x8*)(kr + ks * 32), acc, 0, 0, 0);
        float t[4];
        #pragma unroll
        for (int r = 0; r < 4; r++) {
            t[r] = fast_tanh10(acc[r] * 0.0625f);
            if ((mw[r] >> c) & 1u) mx[r] = fmaxf(mx[r], t[r]);
        }
        tu[2 * c] = pk2(t[0], t[1]);
        tu[2 * c + 1] = pk2(t[2], t[3]);
    }
    #pragma unroll
    for (int r = 0; r < 4; r++)
        #pragma unroll
        for (int o = 1; o < 16; o <<= 1) mx[r] = fmaxf(mx[r], __shfl_xor(mx[r], o));

    float sum[4] = {0.f, 0.f, 0.f, 0.f};
    #pragma unroll
    for (int c = 0; c < 32; c++) {
        float v[4] = {ulo(tu[2 * c]), uhi(tu[2 * c]), ulo(tu[2 * c + 1]), uhi(tu[2 * c + 1])};
        #pragma unroll
        for (int r = 0; r < 4; r++) {
            float bit = (float)((mw[r] >> c) & 1u);
            sum[r] += bit * __expf(v[r] - mx[r]);
        }
    }
    #pragma unroll
    for (int r = 0; r < 4; r++)
        #pragma unroll
        for (int o = 1; o < 16; o <<= 1) sum[r] += __shfl_xor(sum[r], o);
    float lse[4];
    #pragma unroll
    for (int r = 0; r < 4; r++) lse[r] = mx[r] + __logf(sum[r]);

    #pragma unroll
    for (int c = 0; c < 32; c++) {
        float v[4] = {ulo(tu[2 * c]), uhi(tu[2 * c]), ulo(tu[2 * c + 1]), uhi(tu[2 * c + 1])};
        #pragma unroll
        for (int r = 0; r < 4; r++) {
            float ov = ((mw[r] >> c) & 1u) ? v[r] - lse[r] : NEG_INF - lse[r];
            out[((size_t)(b * TT + t0 + 4 * hi + r)) * NN + c * 16 + lo] = ov;
        }
    }
}

// ---------------------------------------------------------------------------
extern "C" void kernel_launch(void* const* d_in, const int* in_sizes, int n_in,
                              void* d_out, int out_size, void* d_ws,
                              size_t ws_size, hipStream_t stream) {
    const float* emb = (const float*)d_in[0];
    const int* cur   = (const int*)d_in[1];
    const int* mask  = (const int*)d_in[2];
    const float* Wn  = (const float*)d_in[3];
    const float* Wf  = (const float*)d_in[4];
    const float* Ws  = (const float*)d_in[5];
    const float* Wo  = (const float*)d_in[6];
    float* out = (float*)d_out;

    const size_t SLABE = (size_t)BB * NN * DD;  // 4,194,304 elements
    ushort* embB     = (ushort*)d_ws;
    ushort* gk       = embB + SLABE;
    ushort* vT       = gk + SLABE;
    ushort* lkb      = vT + SLABE;
    ushort* gq       = lkb + SLABE;
    ushort* headsB   = gq + SLABE;
    ushort* glimpseB = headsB + SLABE;
    ushort* WnT      = glimpseB + SLABE;          // 768*256
    ushort* WsT      = WnT + 768 * 256;           // 256*256
    ushort* WoT      = WsT + 256 * 256;           // 256*256
    uint*   mbt      = (uint*)(WoT + 256 * 256);  // B*T*16
    float*  ctx      = (float*)(mbt + (size_t)BB * TT * 16);  // B*256

    // prep
    cvt_emb_k<<<(int)(SLABE / 4 / 256), 256, 0, stream>>>(emb, embB);
    twt_k<<<dim3(24, 8), dim3(32, 8), 0, stream>>>(Wn, WnT, 768);
    twt_k<<<dim3(8, 8), dim3(32, 8), 0, stream>>>(Ws, WsT, 256);
    twt_k<<<dim3(8, 8), dim3(32, 8), 0, stream>>>(Wo, WoT, 256);
    packmask_k<<<BB * TT * 16 / 256, 256, 0, stream>>>(mask, mbt);
    ctx_k<<<BB, 1024, 0, stream>>>(emb, Wf, ctx);

    // K1: proj = emb @ W_node -> gk / vT / lk
    gemm_mfma_k<0, 0, 1><<<dim3(256, 3), 256, 0, stream>>>(
        embB, WnT, gk, vT, lkb, nullptr, nullptr, 16);
    // K2: glimpse_q = emb[cur] @ W_step + ctx -> gq
    gemm_mfma_k<1, 1, 0><<<dim3(256, 2), 256, 0, stream>>>(
        embB, WsT, gq, nullptr, nullptr, ctx, cur, 8);
    // K3: attention -> headsB
    attn2_k<<<BB * HH * 8, 256, 0, stream>>>(gq, gk, vT, mbt, headsB);
    // K4: glimpse = heads @ W_out
    gemm_mfma_k<0, 0, 0><<<dim3(256, 2), 256, 0, stream>>>(
        headsB, WoT, glimpseB, nullptr, nullptr, nullptr, nullptr, 8);
    // K5: pointer logits + log_softmax
    logits2_k<<<BB * TT / 16, 64, 0, stream>>>(glimpseB, lkb, mbt, out);
}

// Round 4
// 249.105 us; speedup vs baseline: 9.0781x; 1.0667x over previous
//
#include <hip/hip_runtime.h>
#include <hip/hip_bf16.h>

constexpr int BB = 32;    // batch
constexpr int TT = 512;   // decode steps
constexpr int NN = 512;   // nodes
constexpr int DD = 256;   // model dim
constexpr int HH = 8;     // heads
constexpr int DH = 32;    // head dim
#define NEG_INF (-1e9f)

typedef __attribute__((ext_vector_type(8))) short bf16x8;
typedef __attribute__((ext_vector_type(4))) float f32x4;

__device__ inline ushort f2bf(float x) {
    union { float f; unsigned u; } c; c.f = x;
    unsigned u = c.u + 0x7fffu + ((c.u >> 16) & 1u);  // RNE
    return (ushort)(u >> 16);
}
__device__ inline uint pk2(float a, float b) {
    return (uint)f2bf(a) | ((uint)f2bf(b) << 16);
}
__device__ inline float ulo(uint u) {
    union { uint u; float f; } c; c.u = u << 16; return c.f;
}
__device__ inline float uhi(uint u) {
    union { uint u; float f; } c; c.u = u & 0xffff0000u; return c.f;
}
__device__ inline float fast_tanh10(float x) {
    x = fminf(fmaxf(x, -20.f), 20.f);
    float e2 = __expf(2.f * x);
    return 10.f * (1.f - 2.f / (e2 + 1.f));
}

// ---------------------------------------------------------------------------
// P0: emb fp32 -> bf16 (vectorized)
__global__ __launch_bounds__(256) void cvt_emb_k(const float* __restrict__ in,
                                                 ushort* __restrict__ out) {
    int idx = blockIdx.x * 256 + threadIdx.x;
    float4 v = *(const float4*)(in + (size_t)idx * 4);
    ushort4 o = {f2bf(v.x), f2bf(v.y), f2bf(v.z), f2bf(v.w)};
    *(ushort4*)(out + (size_t)idx * 4) = o;
}

// P1: W[256][NC] f32 -> WT[NC][256] bf16
__global__ __launch_bounds__(256) void twt_k(const float* __restrict__ W,
                                             ushort* __restrict__ WT, int NC) {
    __shared__ float t[32][33];
    int tx = threadIdx.x, ty = threadIdx.y;
    int x = blockIdx.x * 32 + tx;
    int y0 = blockIdx.y * 32;
    #pragma unroll
    for (int j = 0; j < 4; j++)
        t[ty + j * 8][tx] = W[(size_t)(y0 + ty + j * 8) * NC + x];
    __syncthreads();
    #pragma unroll
    for (int j = 0; j < 4; j++)
        WT[(size_t)(blockIdx.x * 32 + ty + j * 8) * 256 + y0 + tx] =
            f2bf(t[tx][ty + j * 8]);
}

// P2: mask -> bit-packed mbt [B*T][16]; word w bit c = mask[row][c*16+w]
__global__ __launch_bounds__(256) void packmask_k(const int* __restrict__ mask,
                                                  uint* __restrict__ mbt) {
    int idx = blockIdx.x * 256 + threadIdx.x;
    int row = idx >> 4, w = idx & 15;
    const int* mr = mask + (size_t)row * NN + w;
    uint u = 0;
    #pragma unroll
    for (int c = 0; c < 32; c++) u |= (uint)(mr[c * 16] != 0) << c;
    mbt[idx] = u;
}

// ---------------------------------------------------------------------------
// K0a: partial row sums of emb; grid (BB, 8)
__global__ __launch_bounds__(256) void ctx_sum_k(const float* __restrict__ emb,
                                                 float* __restrict__ partial) {
    int b = blockIdx.x, part = blockIdx.y;
    int d = threadIdx.x;
    const float* eb = emb + ((size_t)b * NN + part * 64) * DD + d;
    float s = 0.f;
    #pragma unroll 8
    for (int i = 0; i < 64; i++) s += eb[(size_t)i * DD];
    partial[((size_t)b * 8 + part) * DD + d] = s;
}
// K0b: ctx = mean @ W_fixed; grid BB
__global__ __launch_bounds__(256) void ctx_mm_k(const float* __restrict__ partial,
                                                const float* __restrict__ Wf,
                                                float* __restrict__ ctx) {
    int b = blockIdx.x, d = threadIdx.x;
    __shared__ float ms[256];
    float s = 0.f;
    #pragma unroll
    for (int p = 0; p < 8; p++) s += partial[((size_t)b * 8 + p) * DD + d];
    ms[d] = s * (1.0f / NN);
    __syncthreads();
    float acc = 0.f;
    #pragma unroll 8
    for (int k = 0; k < 256; k++) acc += ms[k] * Wf[(size_t)k * DD + d];
    ctx[(size_t)b * DD + d] = acc;
}

// ---------------------------------------------------------------------------
// MFMA GEMM: C[M,NC] = A[M,256](bf16) @ W via WT[NC][256] bf16.
// 4 waves x 16 rows; grid (M/64, NCHUNKS/CPB).
template <int GATHER, int BIAS, int SPLIT>
__global__ __launch_bounds__(256) void gemm_mfma_k(
    const ushort* __restrict__ A, const ushort* __restrict__ WT,
    ushort* __restrict__ O0, ushort* __restrict__ O1, ushort* __restrict__ O2,
    const float* __restrict__ bias, const int* __restrict__ gidx, int CPB) {
    int tid = threadIdx.x;
    int w = tid >> 6, l = tid & 63;
    int lo = l & 15, hi = l >> 4;
    int row0 = blockIdx.x * 64 + w * 16;
    int arow = row0 + lo;
    const ushort* ap;
    if (GATHER) {
        int b = arow >> 9;
        int node = gidx[arow];
        ap = A + ((size_t)(b * NN + node)) * DD;
    } else {
        ap = A + (size_t)arow * DD;
    }
    bf16x8 af[8];
    #pragma unroll
    for (int ks = 0; ks < 8; ks++)
        af[ks] = *(const bf16x8*)(ap + ks * 32 + hi * 8);

    const f32x4 zero = {0.f, 0.f, 0.f, 0.f};
    for (int c = 0; c < CPB; c++) {
        int cg = blockIdx.y * CPB + c;
        int col = cg * 16 + lo;
        const ushort* bp = WT + (size_t)col * 256 + hi * 8;
        f32x4 acc = zero;
        #pragma unroll
        for (int ks = 0; ks < 8; ks++)
            acc = __builtin_amdgcn_mfma_f32_16x16x32_bf16(
                af[ks], *(const bf16x8*)(bp + ks * 32), acc, 0, 0, 0);
        float v[4];
        #pragma unroll
        for (int r = 0; r < 4; r++) {
            v[r] = acc[r];
            if (BIAS) v[r] += bias[(size_t)(row0 >> 9) * DD + col];
        }
        if (SPLIT == 0) {
            #pragma unroll
            for (int r = 0; r < 4; r++)
                O0[(size_t)(row0 + 4 * hi + r) * DD + col] = f2bf(v[r]);
        } else {
            if (col < 256) {
                #pragma unroll
                for (int r = 0; r < 4; r++)
                    O0[(size_t)(row0 + 4 * hi + r) * 256 + col] = f2bf(v[r]);
            } else if (col < 512) {
                int cc = col - 256;
                int bh = (row0 >> 9) * HH + (cc >> 5);
                int dh = cc & 31;
                int n0 = (row0 + 4 * hi) & (NN - 1);
                ushort4 uv = {f2bf(v[0]), f2bf(v[1]), f2bf(v[2]), f2bf(v[3])};
                *(ushort4*)(O1 + ((size_t)bh * DH + dh) * NN + n0) = uv;
            } else {
                #pragma unroll
                for (int r = 0; r < 4; r++)
                    O2[(size_t)(row0 + 4 * hi + r) * 256 + (col - 512)] = f2bf(v[r]);
            }
        }
    }
}

// ---------------------------------------------------------------------------
// K3: flash-style MFMA attention. grid = B*H*8, 4 waves x 16 q-rows.
// Per 8-chunk segment: scores (16 packed regs) -> running-max rescale ->
// exp -> P LDS -> PV. O scaled by 1/sum at end.
__global__ __launch_bounds__(256) void attn3_k(
    const ushort* __restrict__ gq, const ushort* __restrict__ gk,
    const ushort* __restrict__ vT, const uint* __restrict__ mbt,
    ushort* __restrict__ headsB) {
    int bid = blockIdx.x;
    int qc = bid & 7, h = (bid >> 3) & 7, b = bid >> 6;
    int tid = threadIdx.x;
    int w = tid >> 6, l = tid & 63;
    int lo = l & 15, hi = l >> 4;
    int t0 = qc * 64 + w * 16;

    __shared__ ushort P[4][16][128];  // 16 KB, wave-private

    bf16x8 qf = *(const bf16x8*)(gq + ((size_t)(b * TT + t0 + lo)) * DD + h * DH + hi * 8);
    uint mw[4];
    #pragma unroll
    for (int r = 0; r < 4; r++)
        mw[r] = mbt[((size_t)(b * TT + t0 + 4 * hi + r)) * 16 + lo];

    const ushort* kb = gk + (size_t)b * NN * DD + h * DH + hi * 8;
    const ushort* vb = vT + ((size_t)(b * HH + h) * DH + lo) * NN + hi * 8;
    const f32x4 zero = {0.f, 0.f, 0.f, 0.f};
    const float sc = 0.17677669529663687f;  // 1/sqrt(32)

    float m[4] = {NEG_INF, NEG_INF, NEG_INF, NEG_INF};
    float sum[4] = {0.f, 0.f, 0.f, 0.f};
    f32x4 o0 = zero, o1 = zero;

    #pragma unroll
    for (int seg = 0; seg < 4; seg++) {
        uint su[16];
        float smx[4] = {m[0], m[1], m[2], m[3]};
        #pragma unroll
        for (int cl = 0; cl < 8; cl++) {
            int c = seg * 8 + cl;
            bf16x8 kf = *(const bf16x8*)(kb + (size_t)(c * 16 + lo) * DD);
            f32x4 s = __builtin_amdgcn_mfma_f32_16x16x32_bf16(qf, kf, zero, 0, 0, 0);
            float v[4];
            #pragma unroll
            for (int r = 0; r < 4; r++) {
                v[r] = ((mw[r] >> c) & 1u) ? s[r] * sc : NEG_INF;
                smx[r] = fmaxf(smx[r], v[r]);
            }
            su[2 * cl] = pk2(v[0], v[1]);
            su[2 * cl + 1] = pk2(v[2], v[3]);
        }
        #pragma unroll
        for (int r = 0; r < 4; r++) {
            #pragma unroll
            for (int o = 1; o < 16; o <<= 1) smx[r] = fmaxf(smx[r], __shfl_xor(smx[r], o));
            float resc = __expf(m[r] - smx[r]);  // m<=smx; both NEG_INF -> 1
            m[r] = smx[r];
            sum[r] *= resc;
            o0[r] *= resc;
            o1[r] *= resc;
        }
        #pragma unroll
        for (int cl = 0; cl < 8; cl++) {
            float v[4] = {ulo(su[2 * cl]), uhi(su[2 * cl]),
                          ulo(su[2 * cl + 1]), uhi(su[2 * cl + 1])};
            int g = 2 * cl + (lo >> 3);
            #pragma unroll
            for (int r = 0; r < 4; r++) {
                float e = __expf(v[r] - m[r]);
                sum[r] += e;
                int row = 4 * hi + r;
                P[w][row][((g ^ (row & 7)) << 3) + (lo & 7)] = f2bf(e);
            }
        }
        #pragma unroll
        for (int c2 = 0; c2 < 4; c2++) {
            int g2 = c2 * 4 + hi;
            bf16x8 pf = *(const bf16x8*)&P[w][lo][(g2 ^ (lo & 7)) << 3];
            bf16x8 vf0 = *(const bf16x8*)(vb + seg * 128 + c2 * 32);
            bf16x8 vf1 = *(const bf16x8*)(vb + (size_t)16 * NN + seg * 128 + c2 * 32);
            o0 = __builtin_amdgcn_mfma_f32_16x16x32_bf16(pf, vf0, o0, 0, 0, 0);
            o1 = __builtin_amdgcn_mfma_f32_16x16x32_bf16(pf, vf1, o1, 0, 0, 0);
        }
    }
    #pragma unroll
    for (int r = 0; r < 4; r++) {
        float inv = 1.0f / sum[r];
        size_t orow = ((size_t)(b * TT + t0 + 4 * hi + r)) * DD + h * DH + lo;
        headsB[orow] = f2bf(o0[r] * inv);
        headsB[orow + 16] = f2bf(o1[r] * inv);
    }
}

// ---------------------------------------------------------------------------
// K5: MFMA pointer logits + log_softmax. 4 waves/block, 16 t-rows/block;
// wave w handles n-chunks w*8..w*8+7; cross-wave max/sum via LDS.
__global__ __launch_bounds__(256) void logits3_k(
    const ushort* __restrict__ glimpse, const ushort* __restrict__ lk,
    const uint* __restrict__ mbt, float* __restrict__ out) {
    int bid = blockIdx.x;  // B*T/16
    int b = bid >> 5;
    int t0 = (bid & 31) * 16;
    int tid = threadIdx.x;
    int w = tid >> 6, l = tid & 63;
    int lo = l & 15, hi = l >> 4;

    __shared__ float redm[4][16];
    __shared__ float reds[4][16];

    bf16x8 af[8];
    const ushort* gb = glimpse + ((size_t)(b * TT + t0 + lo)) * DD + hi * 8;
    #pragma unroll
    for (int ks = 0; ks < 8; ks++) af[ks] = *(const bf16x8*)(gb + ks * 32);
    uint mw[4];
    #pragma unroll
    for (int r = 0; r < 4; r++)
        mw[r] = mbt[((size_t)(b * TT + t0 + 4 * hi + r)) * 16 + lo];

    const f32x4 zero = {0.f, 0.f, 0.f, 0.f};
    const ushort* lkb = lk + (size_t)b * NN * DD + hi * 8;
    float mx[4] = {NEG_INF, NEG_INF, NEG_INF, NEG_INF};
    uint tu[16];
    #pragma unroll
    for (int cl = 0; cl < 8; cl++) {
        int c = w * 8 + cl;
        f32x4 acc = zero;
        const ushort* kr = lkb + (size_t)(c * 16 + lo) * DD;
        #pragma unroll
        for (int ks = 0; ks < 8; ks++)
            acc = __builtin_amdgcn_mfma_f32_16x16x32_bf16(
                af[ks], *(const bf16x8*)(kr + ks * 32), acc, 0, 0, 0);
        float t[4];
        #pragma unroll
        for (int r = 0; r < 4; r++) {
            t[r] = fast_tanh10(acc[r] * 0.0625f);
            if ((mw[r] >> c) & 1u) mx[r] = fmaxf(mx[r], t[r]);
        }
        tu[2 * cl] = pk2(t[0], t[1]);
        tu[2 * cl + 1] = pk2(t[2], t[3]);
    }
    #pragma unroll
    for (int r = 0; r < 4; r++)
        #pragma unroll
        for (int o = 1; o < 16; o <<= 1) mx[r] = fmaxf(mx[r], __shfl_xor(mx[r], o));
    if (lo == 0) {
        #pragma unroll
        for (int r = 0; r < 4; r++) redm[w][4 * hi + r] = mx[r];
    }
    __syncthreads();
    #pragma unroll
    for (int r = 0; r < 4; r++) {
        int row = 4 * hi + r;
        mx[r] = fmaxf(fmaxf(redm[0][row], redm[1][row]),
                      fmaxf(redm[2][row], redm[3][row]));
    }

    float sum[4] = {0.f, 0.f, 0.f, 0.f};
    #pragma unroll
    for (int cl = 0; cl < 8; cl++) {
        int c = w * 8 + cl;
        float v[4] = {ulo(tu[2 * cl]), uhi(tu[2 * cl]),
                      ulo(tu[2 * cl + 1]), uhi(tu[2 * cl + 1])};
        #pragma unroll
        for (int r = 0; r < 4; r++) {
            float bit = (float)((mw[r] >> c) & 1u);
            sum[r] += bit * __expf(v[r] - mx[r]);
        }
    }
    #pragma unroll
    for (int r = 0; r < 4; r++)
        #pragma unroll
        for (int o = 1; o < 16; o <<= 1) sum[r] += __shfl_xor(sum[r], o);
    if (lo == 0) {
        #pragma unroll
        for (int r = 0; r < 4; r++) reds[w][4 * hi + r] = sum[r];
    }
    __syncthreads();
    float lse[4];
    #pragma unroll
    for (int r = 0; r < 4; r++) {
        int row = 4 * hi + r;
        float s = reds[0][row] + reds[1][row] + reds[2][row] + reds[3][row];
        lse[r] = mx[r] + __logf(s);
    }

    #pragma unroll
    for (int cl = 0; cl < 8; cl++) {
        int c = w * 8 + cl;
        float v[4] = {ulo(tu[2 * cl]), uhi(tu[2 * cl]),
                      ulo(tu[2 * cl + 1]), uhi(tu[2 * cl + 1])};
        #pragma unroll
        for (int r = 0; r < 4; r++) {
            float ov = ((mw[r] >> c) & 1u) ? v[r] - lse[r] : NEG_INF - lse[r];
            out[((size_t)(b * TT + t0 + 4 * hi + r)) * NN + c * 16 + lo] = ov;
        }
    }
}

// ---------------------------------------------------------------------------
extern "C" void kernel_launch(void* const* d_in, const int* in_sizes, int n_in,
                              void* d_out, int out_size, void* d_ws,
                              size_t ws_size, hipStream_t stream) {
    const float* emb = (const float*)d_in[0];
    const int* cur   = (const int*)d_in[1];
    const int* mask  = (const int*)d_in[2];
    const float* Wn  = (const float*)d_in[3];
    const float* Wf  = (const float*)d_in[4];
    const float* Ws  = (const float*)d_in[5];
    const float* Wo  = (const float*)d_in[6];
    float* out = (float*)d_out;

    const size_t SLABE = (size_t)BB * NN * DD;
    ushort* embB     = (ushort*)d_ws;
    ushort* gk       = embB + SLABE;
    ushort* vT       = gk + SLABE;
    ushort* lkb      = vT + SLABE;
    ushort* gq       = lkb + SLABE;
    ushort* headsB   = gq + SLABE;
    ushort* glimpseB = headsB + SLABE;
    ushort* WnT      = glimpseB + SLABE;
    ushort* WsT      = WnT + 768 * 256;
    ushort* WoT      = WsT + 256 * 256;
    uint*   mbt      = (uint*)(WoT + 256 * 256);
    float*  ctx      = (float*)(mbt + (size_t)BB * TT * 16);
    float*  partial  = ctx + (size_t)BB * DD;

    // prep
    cvt_emb_k<<<(int)(SLABE / 4 / 256), 256, 0, stream>>>(emb, embB);
    twt_k<<<dim3(24, 8), dim3(32, 8), 0, stream>>>(Wn, WnT, 768);
    twt_k<<<dim3(8, 8), dim3(32, 8), 0, stream>>>(Ws, WsT, 256);
    twt_k<<<dim3(8, 8), dim3(32, 8), 0, stream>>>(Wo, WoT, 256);
    packmask_k<<<BB * TT * 16 / 256, 256, 0, stream>>>(mask, mbt);
    ctx_sum_k<<<dim3(BB, 8), 256, 0, stream>>>(emb, partial);
    ctx_mm_k<<<BB, 256, 0, stream>>>(partial, Wf, ctx);

    // K1: proj = emb @ W_node -> gk / vT / lk
    gemm_mfma_k<0, 0, 1><<<dim3(256, 12), 256, 0, stream>>>(
        embB, WnT, gk, vT, lkb, nullptr, nullptr, 4);
    // K2: glimpse_q = emb[cur] @ W_step + ctx -> gq
    gemm_mfma_k<1, 1, 0><<<dim3(256, 4), 256, 0, stream>>>(
        embB, WsT, gq, nullptr, nullptr, ctx, cur, 4);
    // K3: attention -> headsB
    attn3_k<<<BB * HH * 8, 256, 0, stream>>>(gq, gk, vT, mbt, headsB);
    // K4: glimpse = heads @ W_out
    gemm_mfma_k<0, 0, 0><<<dim3(256, 4), 256, 0, stream>>>(
        headsB, WoT, glimpseB, nullptr, nullptr, nullptr, nullptr, 4);
    // K5: pointer logits + log_softmax
    logits3_k<<<BB * TT / 16, 256, 0, stream>>>(glimpseB, lkb, mbt, out);
}

// Round 5
// 247.744 us; speedup vs baseline: 9.1280x; 1.0055x over previous
//
#include <hip/hip_runtime.h>
#include <hip/hip_bf16.h>

constexpr int BB = 32;    // batch
constexpr int TT = 512;   // decode steps
constexpr int NN = 512;   // nodes
constexpr int DD = 256;   // model dim
constexpr int HH = 8;     // heads
constexpr int DH = 32;    // head dim
#define NEG_INF (-1e9f)

typedef __attribute__((ext_vector_type(8))) short bf16x8;
typedef __attribute__((ext_vector_type(4))) float f32x4;

__device__ inline ushort f2bf(float x) {
    union { float f; unsigned u; } c; c.f = x;
    unsigned u = c.u + 0x7fffu + ((c.u >> 16) & 1u);  // RNE
    return (ushort)(u >> 16);
}
__device__ inline uint pk2(float a, float b) {
    return (uint)f2bf(a) | ((uint)f2bf(b) << 16);
}
__device__ inline float ulo(uint u) {
    union { uint u; float f; } c; c.u = u << 16; return c.f;
}
__device__ inline float uhi(uint u) {
    union { uint u; float f; } c; c.u = u & 0xffff0000u; return c.f;
}
__device__ inline float fast_tanh10(float x) {
    x = fminf(fmaxf(x, -20.f), 20.f);
    float e2 = __expf(2.f * x);
    return 10.f * (1.f - 2.f / (e2 + 1.f));
}

// ---------------------------------------------------------------------------
// P0: emb fp32 -> bf16
__global__ __launch_bounds__(256) void cvt_emb_k(const float* __restrict__ in,
                                                 ushort* __restrict__ out) {
    int idx = blockIdx.x * 256 + threadIdx.x;
    float4 v = *(const float4*)(in + (size_t)idx * 4);
    ushort4 o = {f2bf(v.x), f2bf(v.y), f2bf(v.z), f2bf(v.w)};
    *(ushort4*)(out + (size_t)idx * 4) = o;
}

// P1: W[256][NC] f32 -> WT[NC][256] bf16
__global__ __launch_bounds__(256) void twt_k(const float* __restrict__ W,
                                             ushort* __restrict__ WT, int NC) {
    __shared__ float t[32][33];
    int tx = threadIdx.x, ty = threadIdx.y;
    int x = blockIdx.x * 32 + tx;
    int y0 = blockIdx.y * 32;
    #pragma unroll
    for (int j = 0; j < 4; j++)
        t[ty + j * 8][tx] = W[(size_t)(y0 + ty + j * 8) * NC + x];
    __syncthreads();
    #pragma unroll
    for (int j = 0; j < 4; j++)
        WT[(size_t)(blockIdx.x * 32 + ty + j * 8) * 256 + y0 + tx] =
            f2bf(t[tx][ty + j * 8]);
}

// P2: mask -> bit-packed mbt [B*T][16]; word w bit c = mask[row][c*16+w]
__global__ __launch_bounds__(256) void packmask_k(const int* __restrict__ mask,
                                                  uint* __restrict__ mbt) {
    int idx = blockIdx.x * 256 + threadIdx.x;
    int row = idx >> 4, w = idx & 15;
    const int* mr = mask + (size_t)row * NN + w;
    uint u = 0;
    #pragma unroll
    for (int c = 0; c < 32; c++) u |= (uint)(mr[c * 16] != 0) << c;
    mbt[idx] = u;
}

// ---------------------------------------------------------------------------
// K0a: partial row sums of emb; grid (BB, 8)
__global__ __launch_bounds__(256) void ctx_sum_k(const float* __restrict__ emb,
                                                 float* __restrict__ partial) {
    int b = blockIdx.x, part = blockIdx.y;
    int d = threadIdx.x;
    const float* eb = emb + ((size_t)b * NN + part * 64) * DD + d;
    float s = 0.f;
    #pragma unroll 8
    for (int i = 0; i < 64; i++) s += eb[(size_t)i * DD];
    partial[((size_t)b * 8 + part) * DD + d] = s;
}
// K0b: ctx = mean @ W_fixed; grid BB
__global__ __launch_bounds__(256) void ctx_mm_k(const float* __restrict__ partial,
                                                const float* __restrict__ Wf,
                                                float* __restrict__ ctx) {
    int b = blockIdx.x, d = threadIdx.x;
    __shared__ float ms[256];
    float s = 0.f;
    #pragma unroll
    for (int p = 0; p < 8; p++) s += partial[((size_t)b * 8 + p) * DD + d];
    ms[d] = s * (1.0f / NN);
    __syncthreads();
    float acc = 0.f;
    #pragma unroll 8
    for (int k = 0; k < 256; k++) acc += ms[k] * Wf[(size_t)k * DD + d];
    ctx[(size_t)b * DD + d] = acc;
}

// ---------------------------------------------------------------------------
// MFMA GEMM: C[M,256*?] = A[M,256](bf16) @ W via WT[NC][256] bf16.
// 1-D grid j: x = j&255 (row panel), y = j>>8 (col group). Same-x blocks share
// an XCD (j%8 = x%8) so the A panel stays in one L2 across y.
template <int GATHER, int BIAS, int SPLIT>
__global__ __launch_bounds__(256) void gemm_mfma_k(
    const ushort* __restrict__ A, const ushort* __restrict__ WT,
    ushort* __restrict__ O0, ushort* __restrict__ O1, ushort* __restrict__ O2,
    const float* __restrict__ bias, const int* __restrict__ gidx, int CPB) {
    int j = blockIdx.x;
    int bx = j & 255, by = j >> 8;
    int tid = threadIdx.x;
    int w = tid >> 6, l = tid & 63;
    int lo = l & 15, hi = l >> 4;
    int row0 = bx * 64 + w * 16;
    int arow = row0 + lo;
    const ushort* ap;
    if (GATHER) {
        int b = arow >> 9;
        int node = gidx[arow];
        ap = A + ((size_t)(b * NN + node)) * DD;
    } else {
        ap = A + (size_t)arow * DD;
    }
    bf16x8 af[8];
    #pragma unroll
    for (int ks = 0; ks < 8; ks++)
        af[ks] = *(const bf16x8*)(ap + ks * 32 + hi * 8);

    const f32x4 zero = {0.f, 0.f, 0.f, 0.f};
    for (int c = 0; c < CPB; c++) {
        int cg = by * CPB + c;
        int col = cg * 16 + lo;
        const ushort* bp = WT + (size_t)col * 256 + hi * 8;
        f32x4 acc = zero;
        #pragma unroll
        for (int ks = 0; ks < 8; ks++)
            acc = __builtin_amdgcn_mfma_f32_16x16x32_bf16(
                af[ks], *(const bf16x8*)(bp + ks * 32), acc, 0, 0, 0);
        float v[4];
        #pragma unroll
        for (int r = 0; r < 4; r++) {
            v[r] = acc[r];
            if (BIAS) v[r] += bias[(size_t)(row0 >> 9) * DD + col];
        }
        if (SPLIT == 0) {
            #pragma unroll
            for (int r = 0; r < 4; r++)
                O0[(size_t)(row0 + 4 * hi + r) * DD + col] = f2bf(v[r]);
        } else {
            if (col < 256) {
                #pragma unroll
                for (int r = 0; r < 4; r++)
                    O0[(size_t)(row0 + 4 * hi + r) * 256 + col] = f2bf(v[r]);
            } else if (col < 512) {
                int cc = col - 256;
                int bh = (row0 >> 9) * HH + (cc >> 5);
                int dh = cc & 31;
                int n0 = (row0 + 4 * hi) & (NN - 1);
                ushort4 uv = {f2bf(v[0]), f2bf(v[1]), f2bf(v[2]), f2bf(v[3])};
                *(ushort4*)(O1 + ((size_t)bh * DH + dh) * NN + n0) = uv;
            } else {
                #pragma unroll
                for (int r = 0; r < 4; r++)
                    O2[(size_t)(row0 + 4 * hi + r) * 256 + (col - 512)] = f2bf(v[r]);
            }
        }
    }
}

// ---------------------------------------------------------------------------
// K3: single-pass MFMA attention, no max subtraction (scores bounded ~|12|,
// f32 exp safe to 88). grid j: bh = j&255, qc = j>>8 -> all 8 qc of a (b,h)
// share an XCD. 4 waves x 16 q-rows, wave-private P segments in LDS.
__global__ __launch_bounds__(256) void attn4_k(
    const ushort* __restrict__ gq, const ushort* __restrict__ gk,
    const ushort* __restrict__ vT, const uint* __restrict__ mbt,
    ushort* __restrict__ headsB) {
    int j = blockIdx.x;
    int bh = j & 255, qc = j >> 8;
    int b = bh >> 3, h = bh & 7;
    int tid = threadIdx.x;
    int w = tid >> 6, l = tid & 63;
    int lo = l & 15, hi = l >> 4;
    int t0 = qc * 64 + w * 16;

    __shared__ ushort P[4][16][128];  // 16 KB, wave-private

    bf16x8 qf = *(const bf16x8*)(gq + ((size_t)(b * TT + t0 + lo)) * DD + h * DH + hi * 8);
    uint mw[4];
    #pragma unroll
    for (int r = 0; r < 4; r++)
        mw[r] = mbt[((size_t)(b * TT + t0 + 4 * hi + r)) * 16 + lo];

    const ushort* kb = gk + (size_t)b * NN * DD + h * DH + hi * 8;
    const ushort* vb = vT + ((size_t)(b * HH + h) * DH + lo) * NN + hi * 8;
    const f32x4 zero = {0.f, 0.f, 0.f, 0.f};
    const float sc = 0.17677669529663687f;  // 1/sqrt(32)

    float sum[4] = {0.f, 0.f, 0.f, 0.f};
    f32x4 o0 = zero, o1 = zero;

    #pragma unroll
    for (int seg = 0; seg < 4; seg++) {
        #pragma unroll
        for (int cl = 0; cl < 8; cl++) {
            int c = seg * 8 + cl;
            bf16x8 kf = *(const bf16x8*)(kb + (size_t)(c * 16 + lo) * DD);
            f32x4 s = __builtin_amdgcn_mfma_f32_16x16x32_bf16(qf, kf, zero, 0, 0, 0);
            int g = 2 * cl + (lo >> 3);
            #pragma unroll
            for (int r = 0; r < 4; r++) {
                float e = ((mw[r] >> c) & 1u) ? __expf(s[r] * sc) : 0.f;
                sum[r] += e;
                int row = 4 * hi + r;
                P[w][row][((g ^ (row & 7)) << 3) + (lo & 7)] =
                    (ushort)(__float_as_uint(e) >> 16);  // trunc bf16
            }
        }
        #pragma unroll
        for (int c2 = 0; c2 < 4; c2++) {
            int g2 = c2 * 4 + hi;
            bf16x8 pf = *(const bf16x8*)&P[w][lo][(g2 ^ (lo & 7)) << 3];
            bf16x8 vf0 = *(const bf16x8*)(vb + seg * 128 + c2 * 32);
            bf16x8 vf1 = *(const bf16x8*)(vb + (size_t)16 * NN + seg * 128 + c2 * 32);
            o0 = __builtin_amdgcn_mfma_f32_16x16x32_bf16(pf, vf0, o0, 0, 0, 0);
            o1 = __builtin_amdgcn_mfma_f32_16x16x32_bf16(pf, vf1, o1, 0, 0, 0);
        }
    }
    #pragma unroll
    for (int r = 0; r < 4; r++) {
        #pragma unroll
        for (int o = 1; o < 16; o <<= 1) sum[r] += __shfl_xor(sum[r], o);
    }
    #pragma unroll
    for (int r = 0; r < 4; r++) {
        float inv = 1.0f / fmaxf(sum[r], 1e-30f);
        size_t orow = ((size_t)(b * TT + t0 + 4 * hi + r)) * DD + h * DH + lo;
        headsB[orow] = f2bf(o0[r] * inv);
        headsB[orow + 16] = f2bf(o1[r] * inv);
    }
}

// ---------------------------------------------------------------------------
// K5: MFMA pointer logits + log_softmax with FIXED max = 10 (tanh bound).
// grid j: b = j&31, tc = j>>5 -> one batch's lk panel per XCD.
__global__ __launch_bounds__(256) void logits4_k(
    const ushort* __restrict__ glimpse, const ushort* __restrict__ lk,
    const uint* __restrict__ mbt, float* __restrict__ out) {
    int j = blockIdx.x;  // B * T/16
    int b = j & 31;
    int t0 = (j >> 5) * 16;
    int tid = threadIdx.x;
    int w = tid >> 6, l = tid & 63;
    int lo = l & 15, hi = l >> 4;

    __shared__ float reds[4][16];

    bf16x8 af[8];
    const ushort* gb = glimpse + ((size_t)(b * TT + t0 + lo)) * DD + hi * 8;
    #pragma unroll
    for (int ks = 0; ks < 8; ks++) af[ks] = *(const bf16x8*)(gb + ks * 32);
    uint mw[4];
    #pragma unroll
    for (int r = 0; r < 4; r++)
        mw[r] = mbt[((size_t)(b * TT + t0 + 4 * hi + r)) * 16 + lo];

    const f32x4 zero = {0.f, 0.f, 0.f, 0.f};
    const ushort* lkb = lk + (size_t)b * NN * DD + hi * 8;
    float sum[4] = {0.f, 0.f, 0.f, 0.f};
    uint tu[16];
    #pragma unroll
    for (int cl = 0; cl < 8; cl++) {
        int c = w * 8 + cl;
        f32x4 acc = zero;
        const ushort* kr = lkb + (size_t)(c * 16 + lo) * DD;
        #pragma unroll
        for (int ks = 0; ks < 8; ks++)
            acc = __builtin_amdgcn_mfma_f32_16x16x32_bf16(
                af[ks], *(const bf16x8*)(kr + ks * 32), acc, 0, 0, 0);
        float t[4];
        #pragma unroll
        for (int r = 0; r < 4; r++) {
            t[r] = fast_tanh10(acc[r] * 0.0625f);
            sum[r] += ((mw[r] >> c) & 1u) ? __expf(t[r] - 10.f) : 0.f;
        }
        tu[2 * cl] = pk2(t[0], t[1]);
        tu[2 * cl + 1] = pk2(t[2], t[3]);
    }
    #pragma unroll
    for (int r = 0; r < 4; r++)
        #pragma unroll
        for (int o = 1; o < 16; o <<= 1) sum[r] += __shfl_xor(sum[r], o);
    if (lo == 0) {
        #pragma unroll
        for (int r = 0; r < 4; r++) reds[w][4 * hi + r] = sum[r];
    }
    __syncthreads();
    float lse[4];
    #pragma unroll
    for (int r = 0; r < 4; r++) {
        int row = 4 * hi + r;
        float s = reds[0][row] + reds[1][row] + reds[2][row] + reds[3][row];
        lse[r] = 10.f + __logf(fmaxf(s, 1e-37f));
    }

    #pragma unroll
    for (int cl = 0; cl < 8; cl++) {
        int c = w * 8 + cl;
        float v[4] = {ulo(tu[2 * cl]), uhi(tu[2 * cl]),
                      ulo(tu[2 * cl + 1]), uhi(tu[2 * cl + 1])};
        #pragma unroll
        for (int r = 0; r < 4; r++) {
            float ov = ((mw[r] >> c) & 1u) ? v[r] - lse[r] : NEG_INF - lse[r];
            out[((size_t)(b * TT + t0 + 4 * hi + r)) * NN + c * 16 + lo] = ov;
        }
    }
}

// ---------------------------------------------------------------------------
extern "C" void kernel_launch(void* const* d_in, const int* in_sizes, int n_in,
                              void* d_out, int out_size, void* d_ws,
                              size_t ws_size, hipStream_t stream) {
    const float* emb = (const float*)d_in[0];
    const int* cur   = (const int*)d_in[1];
    const int* mask  = (const int*)d_in[2];
    const float* Wn  = (const float*)d_in[3];
    const float* Wf  = (const float*)d_in[4];
    const float* Ws  = (const float*)d_in[5];
    const float* Wo  = (const float*)d_in[6];
    float* out = (float*)d_out;

    const size_t SLABE = (size_t)BB * NN * DD;
    ushort* embB     = (ushort*)d_ws;
    ushort* gk       = embB + SLABE;
    ushort* vT       = gk + SLABE;
    ushort* lkb      = vT + SLABE;
    ushort* gq       = lkb + SLABE;
    ushort* headsB   = gq + SLABE;
    ushort* glimpseB = headsB + SLABE;
    ushort* WnT      = glimpseB + SLABE;
    ushort* WsT      = WnT + 768 * 256;
    ushort* WoT      = WsT + 256 * 256;
    uint*   mbt      = (uint*)(WoT + 256 * 256);
    float*  ctx      = (float*)(mbt + (size_t)BB * TT * 16);
    float*  partial  = ctx + (size_t)BB * DD;

    // prep
    cvt_emb_k<<<(int)(SLABE / 4 / 256), 256, 0, stream>>>(emb, embB);
    twt_k<<<dim3(24, 8), dim3(32, 8), 0, stream>>>(Wn, WnT, 768);
    twt_k<<<dim3(8, 8), dim3(32, 8), 0, stream>>>(Ws, WsT, 256);
    twt_k<<<dim3(8, 8), dim3(32, 8), 0, stream>>>(Wo, WoT, 256);
    packmask_k<<<BB * TT * 16 / 256, 256, 0, stream>>>(mask, mbt);
    ctx_sum_k<<<dim3(BB, 8), 256, 0, stream>>>(emb, partial);
    ctx_mm_k<<<BB, 256, 0, stream>>>(partial, Wf, ctx);

    // K1: proj = emb @ W_node -> gk / vT / lk   (3072 = 256 x * 12 y)
    gemm_mfma_k<0, 0, 1><<<3072, 256, 0, stream>>>(
        embB, WnT, gk, vT, lkb, nullptr, nullptr, 4);
    // K2: glimpse_q = emb[cur] @ W_step + ctx -> gq   (1024 = 256 x * 4 y)
    gemm_mfma_k<1, 1, 0><<<1024, 256, 0, stream>>>(
        embB, WsT, gq, nullptr, nullptr, ctx, cur, 4);
    // K3: attention -> headsB
    attn4_k<<<BB * HH * 8, 256, 0, stream>>>(gq, gk, vT, mbt, headsB);
    // K4: glimpse = heads @ W_out
    gemm_mfma_k<0, 0, 0><<<1024, 256, 0, stream>>>(
        headsB, WoT, glimpseB, nullptr, nullptr, nullptr, nullptr, 4);
    // K5: pointer logits + log_softmax
    logits4_k<<<BB * TT / 16, 256, 0, stream>>>(glimpseB, lkb, mbt, out);
}

// Round 6
// 239.658 us; speedup vs baseline: 9.4360x; 1.0337x over previous
//
#include <hip/hip_runtime.h>
#include <hip/hip_bf16.h>

constexpr int BB = 32;    // batch
constexpr int TT = 512;   // decode steps
constexpr int NN = 512;   // nodes
constexpr int DD = 256;   // model dim
constexpr int HH = 8;     // heads
constexpr int DH = 32;    // head dim
#define NEG_INF (-1e9f)

typedef __attribute__((ext_vector_type(8))) short bf16x8;
typedef __attribute__((ext_vector_type(4))) float f32x4;

__device__ inline ushort f2bf(float x) {
    union { float f; unsigned u; } c; c.f = x;
    unsigned u = c.u + 0x7fffu + ((c.u >> 16) & 1u);  // RNE
    return (ushort)(u >> 16);
}
__device__ inline uint pk2(float a, float b) {
    return (uint)f2bf(a) | ((uint)f2bf(b) << 16);
}
__device__ inline float ulo(uint u) {
    union { uint u; float f; } c; c.u = u << 16; return c.f;
}
__device__ inline float uhi(uint u) {
    union { uint u; float f; } c; c.u = u & 0xffff0000u; return c.f;
}
__device__ inline float fast_tanh10(float x) {
    x = fminf(fmaxf(x, -20.f), 20.f);
    float e2 = __expf(2.f * x);
    return 10.f * (1.f - 2.f / (e2 + 1.f));
}

// ---------------------------------------------------------------------------
// P0': fused emb fp32->bf16 convert + per-(b,part) partial sums. grid (BB,8).
__global__ __launch_bounds__(256) void cvt_ctx_k(const float* __restrict__ emb,
                                                 ushort* __restrict__ embB,
                                                 float* __restrict__ partial) {
    int b = blockIdx.x, part = blockIdx.y, d = threadIdx.x;
    const float* eb = emb + ((size_t)b * NN + part * 64) * DD + d;
    ushort* ob = embB + ((size_t)b * NN + part * 64) * DD + d;
    float s = 0.f;
    #pragma unroll 4
    for (int i = 0; i < 64; i++) {
        float v = eb[(size_t)i * DD];
        s += v;
        ob[(size_t)i * DD] = f2bf(v);
    }
    partial[((size_t)b * 8 + part) * DD + d] = s;
}

// P1': all three weight transposes in one launch. grid (40, 8), block (32,8).
__global__ void twt_all_k(const float* __restrict__ Wn,
                          const float* __restrict__ Ws,
                          const float* __restrict__ Wo,
                          ushort* __restrict__ WnT, ushort* __restrict__ WsT,
                          ushort* __restrict__ WoT) {
    __shared__ float t[32][33];
    int gx = blockIdx.x;
    const float* W;
    ushort* WT;
    int NC, xb;
    if (gx < 24)      { W = Wn; WT = WnT; NC = 768; xb = gx; }
    else if (gx < 32) { W = Ws; WT = WsT; NC = 256; xb = gx - 24; }
    else              { W = Wo; WT = WoT; NC = 256; xb = gx - 32; }
    int tx = threadIdx.x, ty = threadIdx.y;
    int x = xb * 32 + tx;
    int y0 = blockIdx.y * 32;
    #pragma unroll
    for (int j = 0; j < 4; j++)
        t[ty + j * 8][tx] = W[(size_t)(y0 + ty + j * 8) * NC + x];
    __syncthreads();
    #pragma unroll
    for (int j = 0; j < 4; j++)
        WT[(size_t)(xb * 32 + ty + j * 8) * 256 + y0 + tx] =
            f2bf(t[tx][ty + j * 8]);
}

// P2: mask -> bit-packed mbt [B*T][16]; word w bit c = mask[row][c*16+w]
__global__ __launch_bounds__(256) void packmask_k(const int* __restrict__ mask,
                                                  uint* __restrict__ mbt) {
    int idx = blockIdx.x * 256 + threadIdx.x;
    int row = idx >> 4, w = idx & 15;
    const int* mr = mask + (size_t)row * NN + w;
    uint u = 0;
    #pragma unroll
    for (int c = 0; c < 32; c++) u |= (uint)(mr[c * 16] != 0) << c;
    mbt[idx] = u;
}

// K0b: ctx = mean @ W_fixed; grid BB
__global__ __launch_bounds__(256) void ctx_mm_k(const float* __restrict__ partial,
                                                const float* __restrict__ Wf,
                                                float* __restrict__ ctx) {
    int b = blockIdx.x, d = threadIdx.x;
    __shared__ float ms[256];
    float s = 0.f;
    #pragma unroll
    for (int p = 0; p < 8; p++) s += partial[((size_t)b * 8 + p) * DD + d];
    ms[d] = s * (1.0f / NN);
    __syncthreads();
    float acc = 0.f;
    #pragma unroll 8
    for (int k = 0; k < 256; k++) acc += ms[k] * Wf[(size_t)k * DD + d];
    ctx[(size_t)b * DD + d] = acc;
}

// ---------------------------------------------------------------------------
// MFMA GEMM: C[M,256*?] = A[M,256](bf16) @ W via WT[NC][256] bf16.
// 1-D grid j: x = j&255 (row panel), y = j>>8 (col group).
template <int GATHER, int BIAS, int SPLIT>
__global__ __launch_bounds__(256) void gemm_mfma_k(
    const ushort* __restrict__ A, const ushort* __restrict__ WT,
    ushort* __restrict__ O0, ushort* __restrict__ O1, ushort* __restrict__ O2,
    const float* __restrict__ bias, const int* __restrict__ gidx, int CPB) {
    int j = blockIdx.x;
    int bx = j & 255, by = j >> 8;
    int tid = threadIdx.x;
    int w = tid >> 6, l = tid & 63;
    int lo = l & 15, hi = l >> 4;
    int row0 = bx * 64 + w * 16;
    int arow = row0 + lo;
    const ushort* ap;
    if (GATHER) {
        int b = arow >> 9;
        int node = gidx[arow];
        ap = A + ((size_t)(b * NN + node)) * DD;
    } else {
        ap = A + (size_t)arow * DD;
    }
    bf16x8 af[8];
    #pragma unroll
    for (int ks = 0; ks < 8; ks++)
        af[ks] = *(const bf16x8*)(ap + ks * 32 + hi * 8);

    const f32x4 zero = {0.f, 0.f, 0.f, 0.f};
    for (int c = 0; c < CPB; c++) {
        int cg = by * CPB + c;
        int col = cg * 16 + lo;
        const ushort* bp = WT + (size_t)col * 256 + hi * 8;
        f32x4 acc = zero;
        #pragma unroll
        for (int ks = 0; ks < 8; ks++)
            acc = __builtin_amdgcn_mfma_f32_16x16x32_bf16(
                af[ks], *(const bf16x8*)(bp + ks * 32), acc, 0, 0, 0);
        float v[4];
        #pragma unroll
        for (int r = 0; r < 4; r++) {
            v[r] = acc[r];
            if (BIAS) v[r] += bias[(size_t)(row0 >> 9) * DD + col];
        }
        if (SPLIT == 0) {
            #pragma unroll
            for (int r = 0; r < 4; r++)
                O0[(size_t)(row0 + 4 * hi + r) * DD + col] = f2bf(v[r]);
        } else {
            if (col < 256) {
                #pragma unroll
                for (int r = 0; r < 4; r++)
                    O0[(size_t)(row0 + 4 * hi + r) * 256 + col] = f2bf(v[r]);
            } else if (col < 512) {
                int cc = col - 256;
                int bh = (row0 >> 9) * HH + (cc >> 5);
                int dh = cc & 31;
                int n0 = (row0 + 4 * hi) & (NN - 1);
                ushort4 uv = {f2bf(v[0]), f2bf(v[1]), f2bf(v[2]), f2bf(v[3])};
                *(ushort4*)(O1 + ((size_t)bh * DH + dh) * NN + n0) = uv;
            } else {
                #pragma unroll
                for (int r = 0; r < 4; r++)
                    O2[(size_t)(row0 + 4 * hi + r) * 256 + (col - 512)] = f2bf(v[r]);
            }
        }
    }
}

// ---------------------------------------------------------------------------
// K3: single-pass MFMA attention with deep K/V register prefetch (no max
// subtraction: |s*sc| ~< 12 << 88). Named double-buffers, fully unrolled
// (rule #20: no runtime-indexed reg arrays). grid j: bh = j&255, qc = j>>8.
__global__ __launch_bounds__(256) void attn5_k(
    const ushort* __restrict__ gq, const ushort* __restrict__ gk,
    const ushort* __restrict__ vT, const uint* __restrict__ mbt,
    ushort* __restrict__ headsB) {
    int j = blockIdx.x;
    int bh = j & 255, qc = j >> 8;
    int b = bh >> 3, h = bh & 7;
    int tid = threadIdx.x;
    int w = tid >> 6, l = tid & 63;
    int lo = l & 15, hi = l >> 4;
    int t0 = qc * 64 + w * 16;

    __shared__ ushort P[4][16][128];  // 16 KB, wave-private

    bf16x8 qf = *(const bf16x8*)(gq + ((size_t)(b * TT + t0 + lo)) * DD + h * DH + hi * 8);
    uint mw[4];
    #pragma unroll
    for (int r = 0; r < 4; r++)
        mw[r] = mbt[((size_t)(b * TT + t0 + 4 * hi + r)) * 16 + lo];

    const ushort* kb = gk + (size_t)b * NN * DD + h * DH + hi * 8;
    const ushort* vb = vT + ((size_t)(b * HH + h) * DH + lo) * NN + hi * 8;
    const f32x4 zero = {0.f, 0.f, 0.f, 0.f};
    const float sc = 0.17677669529663687f;  // 1/sqrt(32)

    float sum[4] = {0.f, 0.f, 0.f, 0.f};
    f32x4 o0 = zero, o1 = zero;

#define LDK(DST, SEG)                                                         \
    _Pragma("unroll")                                                         \
    for (int cl = 0; cl < 8; cl++)                                            \
        DST[cl] = *(const bf16x8*)(kb + (size_t)((((SEG) * 8 + cl) * 16) + lo) * DD);
#define LDV(DST, SEG)                                                         \
    _Pragma("unroll")                                                         \
    for (int i = 0; i < 8; i++)                                               \
        DST[i] = *(const bf16x8*)(vb + (size_t)(i >> 2) * 16 * NN + (SEG) * 128 + (i & 3) * 32);
#define SEGBODY(SEG, KC, VC)                                                  \
    {                                                                         \
        f32x4 s[8];                                                           \
        _Pragma("unroll")                                                     \
        for (int cl = 0; cl < 8; cl++)                                        \
            s[cl] = __builtin_amdgcn_mfma_f32_16x16x32_bf16(qf, KC[cl], zero, 0, 0, 0); \
        _Pragma("unroll")                                                     \
        for (int cl = 0; cl < 8; cl++) {                                      \
            int c = (SEG) * 8 + cl;                                           \
            int g = 2 * cl + (lo >> 3);                                       \
            _Pragma("unroll")                                                 \
            for (int r = 0; r < 4; r++) {                                     \
                float e = ((mw[r] >> c) & 1u) ? __expf(s[cl][r] * sc) : 0.f;  \
                sum[r] += e;                                                  \
                int row = 4 * hi + r;                                         \
                P[w][row][((g ^ (row & 7)) << 3) + (lo & 7)] =                \
                    (ushort)(__float_as_uint(e) >> 16);                       \
            }                                                                 \
        }                                                                     \
        _Pragma("unroll")                                                     \
        for (int c2 = 0; c2 < 4; c2++) {                                      \
            int g2 = c2 * 4 + hi;                                             \
            bf16x8 pf = *(const bf16x8*)&P[w][lo][(g2 ^ (lo & 7)) << 3];      \
            o0 = __builtin_amdgcn_mfma_f32_16x16x32_bf16(pf, VC[c2], o0, 0, 0, 0);     \
            o1 = __builtin_amdgcn_mfma_f32_16x16x32_bf16(pf, VC[c2 + 4], o1, 0, 0, 0); \
        }                                                                     \
    }

    bf16x8 kA[8], kB[8], vA[8], vB[8];
    LDK(kA, 0); LDV(vA, 0);      // 16 loads in flight
    LDK(kB, 1); LDV(vB, 1);      // 32 loads in flight
    SEGBODY(0, kA, vA);
    LDK(kA, 2); LDV(vA, 2);      // refill A while B is ready
    SEGBODY(1, kB, vB);
    LDK(kB, 3); LDV(vB, 3);
    SEGBODY(2, kA, vA);
    SEGBODY(3, kB, vB);
#undef LDK
#undef LDV
#undef SEGBODY

    #pragma unroll
    for (int r = 0; r < 4; r++) {
        #pragma unroll
        for (int o = 1; o < 16; o <<= 1) sum[r] += __shfl_xor(sum[r], o);
    }
    #pragma unroll
    for (int r = 0; r < 4; r++) {
        float inv = 1.0f / fmaxf(sum[r], 1e-30f);
        size_t orow = ((size_t)(b * TT + t0 + 4 * hi + r)) * DD + h * DH + lo;
        headsB[orow] = f2bf(o0[r] * inv);
        headsB[orow + 16] = f2bf(o1[r] * inv);
    }
}

// ---------------------------------------------------------------------------
// K5: MFMA pointer logits + log_softmax with FIXED max = 10 (tanh bound).
// grid j: b = j&31, tc = j>>5.
__global__ __launch_bounds__(256) void logits4_k(
    const ushort* __restrict__ glimpse, const ushort* __restrict__ lk,
    const uint* __restrict__ mbt, float* __restrict__ out) {
    int j = blockIdx.x;  // B * T/16
    int b = j & 31;
    int t0 = (j >> 5) * 16;
    int tid = threadIdx.x;
    int w = tid >> 6, l = tid & 63;
    int lo = l & 15, hi = l >> 4;

    __shared__ float reds[4][16];

    bf16x8 af[8];
    const ushort* gb = glimpse + ((size_t)(b * TT + t0 + lo)) * DD + hi * 8;
    #pragma unroll
    for (int ks = 0; ks < 8; ks++) af[ks] = *(const bf16x8*)(gb + ks * 32);
    uint mw[4];
    #pragma unroll
    for (int r = 0; r < 4; r++)
        mw[r] = mbt[((size_t)(b * TT + t0 + 4 * hi + r)) * 16 + lo];

    const f32x4 zero = {0.f, 0.f, 0.f, 0.f};
    const ushort* lkb = lk + (size_t)b * NN * DD + hi * 8;
    float sum[4] = {0.f, 0.f, 0.f, 0.f};
    uint tu[16];
    #pragma unroll
    for (int cl = 0; cl < 8; cl++) {
        int c = w * 8 + cl;
        f32x4 acc = zero;
        const ushort* kr = lkb + (size_t)(c * 16 + lo) * DD;
        #pragma unroll
        for (int ks = 0; ks < 8; ks++)
            acc = __builtin_amdgcn_mfma_f32_16x16x32_bf16(
                af[ks], *(const bf16x8*)(kr + ks * 32), acc, 0, 0, 0);
        float t[4];
        #pragma unroll
        for (int r = 0; r < 4; r++) {
            t[r] = fast_tanh10(acc[r] * 0.0625f);
            sum[r] += ((mw[r] >> c) & 1u) ? __expf(t[r] - 10.f) : 0.f;
        }
        tu[2 * cl] = pk2(t[0], t[1]);
        tu[2 * cl + 1] = pk2(t[2], t[3]);
    }
    #pragma unroll
    for (int r = 0; r < 4; r++)
        #pragma unroll
        for (int o = 1; o < 16; o <<= 1) sum[r] += __shfl_xor(sum[r], o);
    if (lo == 0) {
        #pragma unroll
        for (int r = 0; r < 4; r++) reds[w][4 * hi + r] = sum[r];
    }
    __syncthreads();
    float lse[4];
    #pragma unroll
    for (int r = 0; r < 4; r++) {
        int row = 4 * hi + r;
        float s = reds[0][row] + reds[1][row] + reds[2][row] + reds[3][row];
        lse[r] = 10.f + __logf(fmaxf(s, 1e-37f));
    }

    #pragma unroll
    for (int cl = 0; cl < 8; cl++) {
        int c = w * 8 + cl;
        float v[4] = {ulo(tu[2 * cl]), uhi(tu[2 * cl]),
                      ulo(tu[2 * cl + 1]), uhi(tu[2 * cl + 1])};
        #pragma unroll
        for (int r = 0; r < 4; r++) {
            float ov = ((mw[r] >> c) & 1u) ? v[r] - lse[r] : NEG_INF - lse[r];
            out[((size_t)(b * TT + t0 + 4 * hi + r)) * NN + c * 16 + lo] = ov;
        }
    }
}

// ---------------------------------------------------------------------------
extern "C" void kernel_launch(void* const* d_in, const int* in_sizes, int n_in,
                              void* d_out, int out_size, void* d_ws,
                              size_t ws_size, hipStream_t stream) {
    const float* emb = (const float*)d_in[0];
    const int* cur   = (const int*)d_in[1];
    const int* mask  = (const int*)d_in[2];
    const float* Wn  = (const float*)d_in[3];
    const float* Wf  = (const float*)d_in[4];
    const float* Ws  = (const float*)d_in[5];
    const float* Wo  = (const float*)d_in[6];
    float* out = (float*)d_out;

    const size_t SLABE = (size_t)BB * NN * DD;
    ushort* embB     = (ushort*)d_ws;
    ushort* gk       = embB + SLABE;
    ushort* vT       = gk + SLABE;
    ushort* lkb      = vT + SLABE;
    ushort* gq       = lkb + SLABE;
    ushort* headsB   = gq + SLABE;
    ushort* glimpseB = headsB + SLABE;
    ushort* WnT      = glimpseB + SLABE;
    ushort* WsT      = WnT + 768 * 256;
    ushort* WoT      = WsT + 256 * 256;
    uint*   mbt      = (uint*)(WoT + 256 * 256);
    float*  ctx      = (float*)(mbt + (size_t)BB * TT * 16);
    float*  partial  = ctx + (size_t)BB * DD;

    // prep (fused)
    cvt_ctx_k<<<dim3(BB, 8), 256, 0, stream>>>(emb, embB, partial);
    twt_all_k<<<dim3(40, 8), dim3(32, 8), 0, stream>>>(Wn, Ws, Wo, WnT, WsT, WoT);
    packmask_k<<<BB * TT * 16 / 256, 256, 0, stream>>>(mask, mbt);
    ctx_mm_k<<<BB, 256, 0, stream>>>(partial, Wf, ctx);

    // K1: proj = emb @ W_node -> gk / vT / lk
    gemm_mfma_k<0, 0, 1><<<3072, 256, 0, stream>>>(
        embB, WnT, gk, vT, lkb, nullptr, nullptr, 4);
    // K2: glimpse_q = emb[cur] @ W_step + ctx -> gq
    gemm_mfma_k<1, 1, 0><<<1024, 256, 0, stream>>>(
        embB, WsT, gq, nullptr, nullptr, ctx, cur, 4);
    // K3: attention -> headsB
    attn5_k<<<BB * HH * 8, 256, 0, stream>>>(gq, gk, vT, mbt, headsB);
    // K4: glimpse = heads @ W_out
    gemm_mfma_k<0, 0, 0><<<1024, 256, 0, stream>>>(
        headsB, WoT, glimpseB, nullptr, nullptr, nullptr, nullptr, 4);
    // K5: pointer logits + log_softmax
    logits4_k<<<BB * TT / 16, 256, 0, stream>>>(glimpseB, lkb, mbt, out);
}